// Round 5
// baseline (5449.611 us; speedup 1.0000x reference)
//
#include <hip/hip_runtime.h>
#include <hip/hip_bf16.h>

#define NNODE   2000
#define NG      8
#define EPG     64000
#define TSTEPS  24
#define HOR     10
#define NSTEP   (HOR-1)
#define PITCH   2048          // per-graph node pitch; row 2047 is the zero row
#define ECAP    98304         // padded CSR capacity (ushorts); sum((deg+15)&~15) <= 96000
#define TILES   125           // 2000 / 16

// ---- workspace layout (bytes) ----
#define OFF_DESC    0            // ushort * ECAP = 196,608
#define OFF_HA      196608       // bf16 * NG*PITCH*64 = 2,097,152
#define OFF_HB      2293760
#define OFF_YIN     4390912      // float * NG*PITCH = 65,536
#define OFF_YB      4456448
#define OFF_KA      4521984
#define OFF_KB      4587520
#define OFF_KC      4653056
#define OFF_S4      4718592
#define OFF_DEG     4784128      // int * PITCH
#define OFF_CUR     4792320
#define OFF_ROWP    4800512      // int * (PITCH+1) (+pad)
#define OFF_DINV    4808960      // float * PITCH
#define OFF_MODES   4817152      // int[2]
#define OFF_WF      4817408      // fp32 weights, 12673 floats (+pad)
#define OFF_WFRAG   4868352      // bf16 hi/lo MFMA frags: 3 mats * 8192 shorts = 49,152
#define OFF_BAR     4917504      // unsigned * 1088 barrier state = 4352
// total ~4.93 MB

#define W0OFF 0
#define B0OFF 64
#define W1OFF 128
#define B1OFF 4224
#define W2OFF 4288
#define B2OFF 8384
#define W3OFF 8448
#define B3OFF 12544
#define W4OFF 12608
#define B4OFF 12672
#define WFTOT 12673

typedef __attribute__((ext_vector_type(8))) short short8;
typedef __attribute__((ext_vector_type(8))) unsigned short u16x8;
typedef __attribute__((ext_vector_type(4))) float f32x4;

struct WPtrs { const void* p[10]; };

__device__ inline float tanh_fast(float x) {
    float xc = fminf(fmaxf(x, -15.f), 15.f);
    float e  = __expf(2.f * xc);
    return 1.f - 2.f / (e + 1.f);
}
__device__ inline unsigned short f2bf(float f) {
    unsigned u = __float_as_uint(f);
    u += 0x7fff + ((u >> 16) & 1);
    return (unsigned short)(u >> 16);
}
__device__ inline float bf2f(unsigned short h) {
    return __uint_as_float(((unsigned)h) << 16);
}
__device__ inline int ld_idx(const void* p, long i, int imode) {
    return imode ? (int)((const long long*)p)[i] : ((const int*)p)[i];
}

// ================= setup kernels (unchanged from R4 except k_init) =================

__global__ void k_detect(const void* x, const void* eidx, int* modes) {
    int lane = threadIdx.x;
    const unsigned* xw = (const unsigned*)x;
    unsigned w = xw[lane];
    int ex = (w >> 7) & 0xFF;
    unsigned long long m = __ballot(ex >= 100 && ex <= 145);
    const unsigned* ew = (const unsigned*)eidx;
    unsigned long long m2 = __ballot(ew[2*lane + 1] != 0);
    if (lane == 0) {
        modes[0] = (__popcll(m) >= 48) ? 1 : 0;
        modes[1] = (__popcll(m2) == 0) ? 1 : 0;
    }
}

__global__ void k_init(int* deg, unsigned* bar) {
    int n = blockIdx.x * 256 + threadIdx.x;
    if (n < PITCH) deg[n] = (n < NNODE) ? 1 : 0;
    if (n < 1088) bar[n] = 0;                     // barrier counters/epoch must start at 0
}

__global__ void k_count(const void* eidx, const int* __restrict__ modes, int* deg) {
    int e = blockIdx.x * 256 + threadIdx.x;
    int imode = modes[1];
    int dst = ld_idx(eidx, (long)EPG + e, imode);
    atomicAdd(&deg[dst], 1);
}

__global__ __launch_bounds__(256) void k_scan(const int* __restrict__ deg, int* rowp,
                                              int* cursor, float* dinv) {
    __shared__ int part[256];
    int t = threadIdx.x, base = t * 8;
    int loc[8]; int s = 0;
    #pragma unroll
    for (int k = 0; k < 8; ++k) {
        int d = deg[base + k];
        int p = (d + 15) & ~15;
        loc[k] = p; s += p;
    }
    part[t] = s; __syncthreads();
    for (int off = 1; off < 256; off <<= 1) {
        int v = (t >= off) ? part[t - off] : 0;
        __syncthreads();
        part[t] += v;
        __syncthreads();
    }
    int run = part[t] - s;
    #pragma unroll
    for (int k = 0; k < 8; ++k) {
        rowp[base + k] = run; cursor[base + k] = run;
        int d = deg[base + k];
        dinv[base + k] = (d > 0) ? rsqrtf((float)d) : 0.f;
        run += loc[k];
    }
    if (t == 255) rowp[PITCH] = part[255];
}

__global__ void k_edgefill(unsigned* desc32) {
    int i = blockIdx.x * 256 + threadIdx.x;
    if (i < ECAP / 2) desc32[i] = 0x07FF07FFu;     // sentinel -> zero row 2047
}

__global__ void k_scatter(const void* eidx, const int* __restrict__ modes,
                          int* cursor, unsigned short* desc) {
    int idx = blockIdx.x * 256 + threadIdx.x;
    if (idx >= EPG + NNODE) return;
    int imode = modes[1];
    int s, d;
    if (idx < EPG) { s = ld_idx(eidx, idx, imode); d = ld_idx(eidx, (long)EPG + idx, imode); }
    else           { s = idx - EPG; d = s; }
    int pos = atomicAdd(&cursor[d], 1);
    desc[pos] = (unsigned short)s;
}

__global__ void k_convert(WPtrs wp, float* wf, const int* __restrict__ modes) {
    int idx = blockIdx.x * 256 + threadIdx.x;
    if (idx >= WFTOT) return;
    int fmode = modes[0];
    const int offs[10]  = {W0OFF,B0OFF,W1OFF,B1OFF,W2OFF,B2OFF,W3OFF,B3OFF,W4OFF,B4OFF};
    const int sizes[10] = {64,64,4096,64,4096,64,4096,64,64,1};
    #pragma unroll
    for (int s = 0; s < 10; ++s) {
        if (idx >= offs[s] && idx < offs[s] + sizes[s]) {
            int j = idx - offs[s];
            wf[idx] = fmode ? __bfloat162float(((const __hip_bfloat16*)wp.p[s])[j])
                            : ((const float*)wp.p[s])[j];
        }
    }
}

__global__ void k_mkfrag(const float* __restrict__ wf, short8* frag) {
    int t = blockIdx.x * 256 + threadIdx.x;
    if (t >= 3072) return;
    int lane = t & 63, half = (t >> 6) & 1, kh = (t >> 7) & 1, nb = (t >> 8) & 3, mat = t >> 10;
    const int woffs[3] = {W1OFF, W2OFF, W3OFF};
    const float* W = wf + woffs[mat];
    int n  = nb * 16 + (lane & 15);
    int k0 = kh * 32 + (lane >> 4) * 8;
    short8 v;
    #pragma unroll
    for (int j = 0; j < 8; ++j) {
        float w = W[(k0 + j) * 64 + n];
        unsigned short h = f2bf(w);
        v[j] = half ? (short)f2bf(w - bf2f(h)) : (short)h;
    }
    frag[t] = v;
}

__global__ void k_hpad(unsigned* hA32, unsigned* hB32) {
    int idx = blockIdx.x * 256 + threadIdx.x;
    if (idx >= 2 * NG * 48 * 32) return;
    int b = idx / (NG * 48 * 32), r = idx % (NG * 48 * 32);
    int g = r / (48 * 32), rr = r % (48 * 32);
    int row = NNODE + rr / 32, fp = rr % 32;
    unsigned* p = b ? hB32 : hA32;
    p[(g * PITCH + row) * 32 + fp] = 0;
}

__global__ void k_finalize(const float* __restrict__ dinv, const void* x,
                           const int* __restrict__ modes,
                           float* yin, float* yb, float* s4, void* out) {
    int idx = blockIdx.x * 256 + threadIdx.x;
    if (idx >= NG * PITCH) return;
    int g = idx >> 11, local = idx & (PITCH - 1);
    if (local >= NNODE) { yin[idx] = 0.f; yb[idx] = 0.f; s4[idx] = 0.f; return; }
    int cn = g * NNODE + local;
    float y0 = modes[0] ? __bfloat162float(((const __hip_bfloat16*)x)[cn * TSTEPS + (TSTEPS - 1)])
                        : ((const float*)x)[cn * TSTEPS + (TSTEPS - 1)];
    yin[idx] = dinv[local] * y0;
    yb[idx]  = y0;
    if (modes[0]) ((__hip_bfloat16*)out)[cn * HOR] = __float2bfloat16(y0);
    else          ((float*)out)[cn * HOR] = y0;
}

// ================= persistent ODE kernel =================

// Two-level monotonic-epoch grid barrier. Agent-scope release on arrival
// (flushes this block's writes), relaxed spin (no per-poll L2 invalidate),
// one acquire fence on exit. Correct regardless of block->XCD mapping.
__device__ __forceinline__ void grid_barrier(unsigned* bar, unsigned be, int tid) {
    __syncthreads();
    if (tid == 0) {
        int bidx = blockIdx.x, grid = gridDim.x;
        int grp = bidx >> 5;
        unsigned ngrp = (unsigned)((grid + 31) >> 5);
        int rem = grid - (grp << 5);
        unsigned gsz = (unsigned)(rem >= 32 ? 32 : rem);
        unsigned* cnt  = bar + grp * 32;        // one 128B line per group
        unsigned* root = bar + 1024;
        unsigned* ep   = bar + 1056;
        if (__hip_atomic_fetch_add(cnt, 1u, __ATOMIC_ACQ_REL, __HIP_MEMORY_SCOPE_AGENT) + 1u == be * gsz) {
            if (__hip_atomic_fetch_add(root, 1u, __ATOMIC_ACQ_REL, __HIP_MEMORY_SCOPE_AGENT) + 1u == be * ngrp) {
                __hip_atomic_store(ep, be, __ATOMIC_RELEASE, __HIP_MEMORY_SCOPE_AGENT);
            }
        }
        while (__hip_atomic_load(ep, __ATOMIC_RELAXED, __HIP_MEMORY_SCOPE_AGENT) < be)
            __builtin_amdgcn_s_sleep(2);
        __threadfence();                        // acquire: invalidate L1/L2
    }
    __syncthreads();
}

__device__ __forceinline__ void l0_phase(
        const float* __restrict__ yg, unsigned short* __restrict__ og,
        const unsigned short* __restrict__ desc, const int* __restrict__ rowp,
        const float* __restrict__ dinv, const float* __restrict__ wf,
        int lane, int wv, int l, int nbg) {
    float w0 = wf[W0OFF + lane], b0 = wf[B0OFF + lane];
    for (int t = l; t < TILES; t += nbg) {
        int tb = t << 4;
        #pragma unroll
        for (int r = 0; r < 4; ++r) {
            int local = tb + (wv << 2) + r;
            int s = rowp[local], e = rowp[local + 1];
            float acc = 0.f;
            for (int i = s + lane; i < e; i += 64) acc += yg[desc[i]];
            #pragma unroll
            for (int off = 32; off; off >>= 1) acc += __shfl_xor(acc, off);
            float dv = dinv[local];
            float o = dv * tanh_fast(dv * acc * w0 + b0);
            og[((size_t)local << 6) + lane] = f2bf(o);
        }
    }
}

template<int FUSE>
__device__ __forceinline__ void heavy_phase(
        const unsigned short* __restrict__ hg, unsigned short* __restrict__ og,
        float* __restrict__ sg,
        const unsigned short* __restrict__ desc, const int* __restrict__ rowp,
        const float* __restrict__ dinv, const float* __restrict__ wf,
        const short8* __restrict__ frag, int mat, int boff,
        int lane, int wv, int l, int nbg, int tid,
        float* tile, float* dinvt, float (*pd)[16]) {
    const short8* fb = frag + (mat << 10);
    short8 Bh0 = fb[(wv << 8) +   0 + lane];
    short8 Bl0 = fb[(wv << 8) +  64 + lane];
    short8 Bh1 = fb[(wv << 8) + 128 + lane];
    short8 Bl1 = fb[(wv << 8) + 192 + lane];
    int mrow = lane & 15, quad = lane >> 4;
    float bias = wf[boff + (wv << 4) + mrow];
    float w4v = FUSE ? wf[W4OFF + (wv << 4) + mrow] : 0.f;

    for (int t = l; t < TILES; t += nbg) {
        int tb = t << 4;
        #pragma unroll
        for (int r = 0; r < 4; ++r) {
            int m = (wv << 2) + r;
            int local = tb + m;
            int s = rowp[local], e = rowp[local + 1];   // multiples of 16
            float acc = 0.f;
            for (int i = s; i < e; i += 16) {
                u16x8 d0 = *(const u16x8*)(desc + i);
                u16x8 d1 = *(const u16x8*)(desc + i + 8);
                unsigned short v[16];
                #pragma unroll
                for (int k = 0; k < 8; ++k) v[k]     = hg[(((unsigned)d0[k]) << 6) + lane];
                #pragma unroll
                for (int k = 0; k < 8; ++k) v[8 + k] = hg[(((unsigned)d1[k]) << 6) + lane];
                #pragma unroll
                for (int k = 0; k < 16; ++k) acc += bf2f(v[k]);
            }
            float dv = dinv[local];
            tile[m * 68 + lane] = acc * dv;
            if (lane == 0) dinvt[m] = dv;
        }
        __syncthreads();

        const float* arow = &tile[mrow * 68];
        float4 a0 = *(const float4*)(arow + (quad << 3));
        float4 a1 = *(const float4*)(arow + (quad << 3) + 4);
        float4 a2 = *(const float4*)(arow + 32 + (quad << 3));
        float4 a3 = *(const float4*)(arow + 32 + (quad << 3) + 4);
        float av0[8] = {a0.x, a0.y, a0.z, a0.w, a1.x, a1.y, a1.z, a1.w};
        float av1[8] = {a2.x, a2.y, a2.z, a2.w, a3.x, a3.y, a3.z, a3.w};
        short8 Ah0, Al0, Ah1, Al1;
        #pragma unroll
        for (int j = 0; j < 8; ++j) {
            unsigned short h0 = f2bf(av0[j]);
            Ah0[j] = (short)h0; Al0[j] = (short)f2bf(av0[j] - bf2f(h0));
            unsigned short h1 = f2bf(av1[j]);
            Ah1[j] = (short)h1; Al1[j] = (short)f2bf(av1[j] - bf2f(h1));
        }
        f32x4 c = {bias, bias, bias, bias};
        c = __builtin_amdgcn_mfma_f32_16x16x32_bf16(Ah0, Bh0, c, 0, 0, 0);
        c = __builtin_amdgcn_mfma_f32_16x16x32_bf16(Al0, Bh0, c, 0, 0, 0);
        c = __builtin_amdgcn_mfma_f32_16x16x32_bf16(Ah0, Bl0, c, 0, 0, 0);
        c = __builtin_amdgcn_mfma_f32_16x16x32_bf16(Ah1, Bh1, c, 0, 0, 0);
        c = __builtin_amdgcn_mfma_f32_16x16x32_bf16(Al1, Bh1, c, 0, 0, 0);
        c = __builtin_amdgcn_mfma_f32_16x16x32_bf16(Ah1, Bl1, c, 0, 0, 0);

        if (!FUSE) {
            #pragma unroll
            for (int r = 0; r < 4; ++r) {
                int m = (quad << 2) + r;
                og[((size_t)(tb + m) << 6) + (wv << 4) + mrow] = f2bf(dinvt[m] * tanh_fast(c[r]));
            }
            __syncthreads();                    // protect tile reuse across t-iterations
        } else {
            #pragma unroll
            for (int r = 0; r < 4; ++r) {
                float d = tanh_fast(c[r]) * w4v;
                d += __shfl_xor(d, 1); d += __shfl_xor(d, 2);
                d += __shfl_xor(d, 4); d += __shfl_xor(d, 8);
                if (mrow == 0) pd[wv][(quad << 2) + r] = d;
            }
            __syncthreads();
            if (tid < 16)
                sg[tb + tid] = dinvt[tid] * (pd[0][tid] + pd[1][tid] + pd[2][tid] + pd[3][tid]);
            __syncthreads();
        }
    }
}

__device__ __forceinline__ void prop_phase(
        const float* __restrict__ sg, const unsigned short* __restrict__ desc,
        const int* __restrict__ rowp, const float* __restrict__ dinv,
        const float* __restrict__ wf,
        float* yin, float* yb, float* kA, float* kB, float* kC,
        float c1, float c2, float c3, float c4, int stage, int fmode,
        void* out, int hidx, int g, int lane, int wv, int l, int nbg) {
    float b4 = wf[B4OFF];
    for (int t = l; t < TILES; t += nbg) {
        int tb = t << 4;
        #pragma unroll
        for (int r = 0; r < 4; ++r) {
            int local = tb + (wv << 2) + r;
            int s = rowp[local], e = rowp[local + 1];
            float acc = 0.f;
            for (int i = s + lane; i < e; i += 64) acc += sg[desc[i]];
            #pragma unroll
            for (int off = 32; off; off >>= 1) acc += __shfl_xor(acc, off);
            if (lane == 0) {
                int idx = g * PITCH + local;
                float dv = dinv[local];
                float k = dv * acc + b4;
                float ynew = yb[idx] + c1 * kA[idx] + c2 * kB[idx] + c3 * kC[idx] + c4 * k;
                if (stage == 0) kA[idx] = k;
                else if (stage == 1) kB[idx] = k;
                else if (stage == 2) kC[idx] = k;
                yin[idx] = dv * ynew;
                if (stage == 3) {
                    yb[idx] = ynew;
                    int cn = g * NNODE + local;
                    if (fmode) ((__hip_bfloat16*)out)[cn * HOR + hidx] = __float2bfloat16(ynew);
                    else       ((float*)out)[cn * HOR + hidx] = ynew;
                }
            }
        }
    }
}

__global__ __launch_bounds__(256, 4) void k_ode(
        unsigned short* hA, unsigned short* hB, float* yin, float* yb,
        float* kA, float* kB, float* kC, float* s4,
        const unsigned short* desc, const int* rowp, const float* dinv,
        const float* wf, const short8* frag, const int* modes, void* out,
        unsigned* bar) {
    __shared__ float tile[16 * 68];
    __shared__ float dinvt[16];
    __shared__ float pd[4][16];
    int tid = threadIdx.x, lane = tid & 63, wv = tid >> 6;
    int b = blockIdx.x, g = b & 7, l = b >> 3, nbg = gridDim.x >> 3;
    int fmode = modes[0];
    unsigned short* hAg = hA + ((size_t)g * PITCH << 6);
    unsigned short* hBg = hB + ((size_t)g * PITCH << 6);
    const float* ying = yin + g * PITCH;
    float* s4g = s4 + g * PITCH;
    unsigned be = 0;

    const float dt = 10.f / 9.f, dt3 = dt / 3.f;
    const float C1[4] = {0.f,  -dt3, dt,  dt * 0.125f};
    const float C2[4] = {0.f,  0.f,  -dt, dt * 0.375f};
    const float C3[4] = {0.f,  0.f,  0.f, dt * 0.375f};
    const float C4[4] = {dt3,  dt,   dt,  dt * 0.125f};

    for (int step = 0; step < NSTEP; ++step) {
        for (int st = 0; st < 4; ++st) {
            l0_phase(ying, hAg, desc, rowp, dinv, wf, lane, wv, l, nbg);
            ++be; grid_barrier(bar, be, tid);
            heavy_phase<0>(hAg, hBg, nullptr, desc, rowp, dinv, wf, frag, 0, B1OFF,
                           lane, wv, l, nbg, tid, tile, dinvt, pd);
            ++be; grid_barrier(bar, be, tid);
            heavy_phase<0>(hBg, hAg, nullptr, desc, rowp, dinv, wf, frag, 1, B2OFF,
                           lane, wv, l, nbg, tid, tile, dinvt, pd);
            ++be; grid_barrier(bar, be, tid);
            heavy_phase<1>(hAg, nullptr, s4g, desc, rowp, dinv, wf, frag, 2, B3OFF,
                           lane, wv, l, nbg, tid, tile, dinvt, pd);
            ++be; grid_barrier(bar, be, tid);
            prop_phase(s4g, desc, rowp, dinv, wf, yin, yb, kA, kB, kC,
                       C1[st], C2[st], C3[st], C4[st], st, fmode, out, step + 1,
                       g, lane, wv, l, nbg);
            ++be; grid_barrier(bar, be, tid);
        }
    }
}

// ================= host =================

extern "C" void kernel_launch(void* const* d_in, const int* in_sizes, int n_in,
                              void* d_out, int out_size, void* d_ws, size_t ws_size,
                              hipStream_t stream) {
    char* ws = (char*)d_ws;
    unsigned short* desc = (unsigned short*)(ws + OFF_DESC);
    unsigned short* hA   = (unsigned short*)(ws + OFF_HA);
    unsigned short* hB   = (unsigned short*)(ws + OFF_HB);
    float* yin  = (float*)(ws + OFF_YIN);
    float* yb   = (float*)(ws + OFF_YB);
    float* kA   = (float*)(ws + OFF_KA);
    float* kB   = (float*)(ws + OFF_KB);
    float* kC   = (float*)(ws + OFF_KC);
    float* s4   = (float*)(ws + OFF_S4);
    int*   deg  = (int*)(ws + OFF_DEG);
    int*   cur  = (int*)(ws + OFF_CUR);
    int*   rowp = (int*)(ws + OFF_ROWP);
    float* dinv = (float*)(ws + OFF_DINV);
    int*   modes= (int*)(ws + OFF_MODES);
    float* wf   = (float*)(ws + OFF_WF);
    short8* wfrag = (short8*)(ws + OFF_WFRAG);
    unsigned* bar = (unsigned*)(ws + OFF_BAR);

    const void* x    = d_in[0];
    const void* eidx = d_in[1];
    WPtrs wp;
    for (int i = 0; i < 10; ++i) wp.p[i] = d_in[2 + i];

    k_detect  <<<1, 64, 0, stream>>>(x, eidx, modes);
    k_init    <<<PITCH / 256, 256, 0, stream>>>(deg, bar);
    k_count   <<<EPG / 256, 256, 0, stream>>>(eidx, modes, deg);
    k_scan    <<<1, 256, 0, stream>>>(deg, rowp, cur, dinv);
    k_edgefill<<<(ECAP / 2 + 255) / 256, 256, 0, stream>>>((unsigned*)desc);
    k_scatter <<<(EPG + NNODE + 255) / 256, 256, 0, stream>>>(eidx, modes, cur, desc);
    k_convert <<<(WFTOT + 255) / 256, 256, 0, stream>>>(wp, wf, modes);
    k_mkfrag  <<<12, 256, 0, stream>>>(wf, wfrag);
    k_hpad    <<<96, 256, 0, stream>>>((unsigned*)hA, (unsigned*)hB);
    k_finalize<<<NG * PITCH / 256, 256, 0, stream>>>(dinv, x, modes, yin, yb, s4, d_out);

    // co-residency-validated persistent launch
    int nCU = 256, occ = 4;
    hipDeviceGetAttribute(&nCU, hipDeviceAttributeMultiprocessorCount, 0);
    hipOccupancyMaxActiveBlocksPerMultiprocessor(&occ, k_ode, 256, 0);
    if (occ < 1) occ = 1;
    int grid = occ * nCU;
    if (grid > 1000) grid = 1000;
    grid &= ~7;                                   // graph distribution needs %8==0
    if (grid < 8) grid = 8;

    void* outp = d_out;
    void* args[] = { &hA, &hB, &yin, &yb, &kA, &kB, &kC, &s4,
                     &desc, &rowp, &dinv, &wf, &wfrag, &modes, &outp, &bar };
    hipLaunchCooperativeKernel((const void*)k_ode, dim3(grid), dim3(256), args, 0, stream);
}

// Round 6
// 5157.359 us; speedup vs baseline: 1.0567x; 1.0567x over previous
//
#include <hip/hip_runtime.h>
#include <hip/hip_bf16.h>

#define NNODE   2000
#define NG      8
#define EPG     64000
#define TSTEPS  24
#define HOR     10
#define NSTEP   (HOR-1)
#define PITCH   2048          // per-graph node pitch; row 2047 is the zero row
#define ECAP    98304         // padded CSR capacity (ushorts); sum((deg+15)&~15) <= 96000
#define TILES   125           // 2000 / 16

// ---- workspace layout (bytes) ----
#define OFF_DESC    0            // ushort * ECAP = 196,608
#define OFF_HA      196608       // bf16 * NG*PITCH*64 = 2,097,152
#define OFF_HB      2293760
#define OFF_YIN     4390912      // float * NG*PITCH = 65,536
#define OFF_YB      4456448
#define OFF_KA      4521984
#define OFF_KB      4587520
#define OFF_KC      4653056
#define OFF_S4      4718592
#define OFF_DEG     4784128      // int * PITCH
#define OFF_CUR     4792320
#define OFF_ROWP    4800512      // int * (PITCH+1) (+pad)
#define OFF_DINV    4808960      // float * PITCH
#define OFF_MODES   4817152      // int[2]
#define OFF_WF      4817408      // fp32 weights, 12673 floats (+pad)
#define OFF_WFRAG   4868352      // bf16 hi/lo MFMA frags: 3 mats * 8192 shorts = 49,152
#define OFF_BAR     4917504      // unsigned * 8*256 per-graph barrier lines = 8192
// total ~4.93 MB

#define W0OFF 0
#define B0OFF 64
#define W1OFF 128
#define B1OFF 4224
#define W2OFF 4288
#define B2OFF 8384
#define W3OFF 8448
#define B3OFF 12544
#define W4OFF 12608
#define B4OFF 12672
#define WFTOT 12673

typedef __attribute__((ext_vector_type(8))) short short8;
typedef __attribute__((ext_vector_type(8))) unsigned short u16x8;
typedef __attribute__((ext_vector_type(4))) float f32x4;

struct WPtrs { const void* p[10]; };

__device__ inline float tanh_fast(float x) {
    float xc = fminf(fmaxf(x, -15.f), 15.f);
    float e  = __expf(2.f * xc);
    return 1.f - 2.f / (e + 1.f);
}
__device__ inline unsigned short f2bf(float f) {
    unsigned u = __float_as_uint(f);
    u += 0x7fff + ((u >> 16) & 1);
    return (unsigned short)(u >> 16);
}
__device__ inline float bf2f(unsigned short h) {
    return __uint_as_float(((unsigned)h) << 16);
}
__device__ inline int ld_idx(const void* p, long i, int imode) {
    return imode ? (int)((const long long*)p)[i] : ((const int*)p)[i];
}

// ================= setup kernels =================

__global__ void k_detect(const void* x, const void* eidx, int* modes) {
    int lane = threadIdx.x;
    const unsigned* xw = (const unsigned*)x;
    unsigned w = xw[lane];
    int ex = (w >> 7) & 0xFF;
    unsigned long long m = __ballot(ex >= 100 && ex <= 145);
    const unsigned* ew = (const unsigned*)eidx;
    unsigned long long m2 = __ballot(ew[2*lane + 1] != 0);
    if (lane == 0) {
        modes[0] = (__popcll(m) >= 48) ? 1 : 0;
        modes[1] = (__popcll(m2) == 0) ? 1 : 0;
    }
}

__global__ void k_init(int* deg, unsigned* bar) {
    int n = blockIdx.x * 256 + threadIdx.x;
    if (n < PITCH) deg[n] = (n < NNODE) ? 1 : 0;
    if (n < NG * 256) bar[n] = 0;                 // all per-graph barrier state -> 0
}

__global__ void k_count(const void* eidx, const int* __restrict__ modes, int* deg) {
    int e = blockIdx.x * 256 + threadIdx.x;
    int imode = modes[1];
    int dst = ld_idx(eidx, (long)EPG + e, imode);
    atomicAdd(&deg[dst], 1);
}

__global__ __launch_bounds__(256) void k_scan(const int* __restrict__ deg, int* rowp,
                                              int* cursor, float* dinv) {
    __shared__ int part[256];
    int t = threadIdx.x, base = t * 8;
    int loc[8]; int s = 0;
    #pragma unroll
    for (int k = 0; k < 8; ++k) {
        int d = deg[base + k];
        int p = (d + 15) & ~15;
        loc[k] = p; s += p;
    }
    part[t] = s; __syncthreads();
    for (int off = 1; off < 256; off <<= 1) {
        int v = (t >= off) ? part[t - off] : 0;
        __syncthreads();
        part[t] += v;
        __syncthreads();
    }
    int run = part[t] - s;
    #pragma unroll
    for (int k = 0; k < 8; ++k) {
        rowp[base + k] = run; cursor[base + k] = run;
        int d = deg[base + k];
        dinv[base + k] = (d > 0) ? rsqrtf((float)d) : 0.f;
        run += loc[k];
    }
    if (t == 255) rowp[PITCH] = part[255];
}

__global__ void k_edgefill(unsigned* desc32) {
    int i = blockIdx.x * 256 + threadIdx.x;
    if (i < ECAP / 2) desc32[i] = 0x07FF07FFu;     // sentinel -> zero row 2047
}

__global__ void k_scatter(const void* eidx, const int* __restrict__ modes,
                          int* cursor, unsigned short* desc) {
    int idx = blockIdx.x * 256 + threadIdx.x;
    if (idx >= EPG + NNODE) return;
    int imode = modes[1];
    int s, d;
    if (idx < EPG) { s = ld_idx(eidx, idx, imode); d = ld_idx(eidx, (long)EPG + idx, imode); }
    else           { s = idx - EPG; d = s; }
    int pos = atomicAdd(&cursor[d], 1);
    desc[pos] = (unsigned short)s;
}

__global__ void k_convert(WPtrs wp, float* wf, const int* __restrict__ modes) {
    int idx = blockIdx.x * 256 + threadIdx.x;
    if (idx >= WFTOT) return;
    int fmode = modes[0];
    const int offs[10]  = {W0OFF,B0OFF,W1OFF,B1OFF,W2OFF,B2OFF,W3OFF,B3OFF,W4OFF,B4OFF};
    const int sizes[10] = {64,64,4096,64,4096,64,4096,64,64,1};
    #pragma unroll
    for (int s = 0; s < 10; ++s) {
        if (idx >= offs[s] && idx < offs[s] + sizes[s]) {
            int j = idx - offs[s];
            wf[idx] = fmode ? __bfloat162float(((const __hip_bfloat16*)wp.p[s])[j])
                            : ((const float*)wp.p[s])[j];
        }
    }
}

__global__ void k_mkfrag(const float* __restrict__ wf, short8* frag) {
    int t = blockIdx.x * 256 + threadIdx.x;
    if (t >= 3072) return;
    int lane = t & 63, half = (t >> 6) & 1, kh = (t >> 7) & 1, nb = (t >> 8) & 3, mat = t >> 10;
    const int woffs[3] = {W1OFF, W2OFF, W3OFF};
    const float* W = wf + woffs[mat];
    int n  = nb * 16 + (lane & 15);
    int k0 = kh * 32 + (lane >> 4) * 8;
    short8 v;
    #pragma unroll
    for (int j = 0; j < 8; ++j) {
        float w = W[(k0 + j) * 64 + n];
        unsigned short h = f2bf(w);
        v[j] = half ? (short)f2bf(w - bf2f(h)) : (short)h;
    }
    frag[t] = v;
}

__global__ void k_hpad(unsigned* hA32, unsigned* hB32) {
    int idx = blockIdx.x * 256 + threadIdx.x;
    if (idx >= 2 * NG * 48 * 32) return;
    int b = idx / (NG * 48 * 32), r = idx % (NG * 48 * 32);
    int g = r / (48 * 32), rr = r % (48 * 32);
    int row = NNODE + rr / 32, fp = rr % 32;
    unsigned* p = b ? hB32 : hA32;
    p[(g * PITCH + row) * 32 + fp] = 0;
}

__global__ void k_finalize(const float* __restrict__ dinv, const void* x,
                           const int* __restrict__ modes,
                           float* yin, float* yb, float* s4, void* out) {
    int idx = blockIdx.x * 256 + threadIdx.x;
    if (idx >= NG * PITCH) return;
    int g = idx >> 11, local = idx & (PITCH - 1);
    if (local >= NNODE) { yin[idx] = 0.f; yb[idx] = 0.f; s4[idx] = 0.f; return; }
    int cn = g * NNODE + local;
    float y0 = modes[0] ? __bfloat162float(((const __hip_bfloat16*)x)[cn * TSTEPS + (TSTEPS - 1)])
                        : ((const float*)x)[cn * TSTEPS + (TSTEPS - 1)];
    yin[idx] = dinv[local] * y0;
    yb[idx]  = y0;
    if (modes[0]) ((__hip_bfloat16*)out)[cn * HOR] = __float2bfloat16(y0);
    else          ((float*)out)[cn * HOR] = y0;
}

// ================= persistent ODE kernel =================

// Per-graph single-level barrier: syncs only the nbg blocks of graph g.
// 8 independent lines 1 KiB apart (cnt at +0, epoch at +64 -> different 256B
// sectors). Arrival: acq_rel atomicAdd; last arrival release-stores epoch;
// <=128 relaxed agent-scope spinners per line with s_sleep backoff (R5's
// failure: 1000 spinners on ONE line -> L3 queuing -> 8 ms).
__device__ __forceinline__ void graph_barrier(unsigned* bar, int g, unsigned be,
                                              unsigned nbg, int tid) {
    __syncthreads();
    if (tid == 0) {
        unsigned* cnt = bar + (g << 8);
        unsigned* ep  = bar + (g << 8) + 64;
        if (__hip_atomic_fetch_add(cnt, 1u, __ATOMIC_ACQ_REL, __HIP_MEMORY_SCOPE_AGENT) + 1u == be * nbg) {
            __hip_atomic_store(ep, be, __ATOMIC_RELEASE, __HIP_MEMORY_SCOPE_AGENT);
        }
        while (__hip_atomic_load(ep, __ATOMIC_RELAXED, __HIP_MEMORY_SCOPE_AGENT) < be)
            __builtin_amdgcn_s_sleep(4);
        __threadfence();                        // acquire: invalidate stale cached lines
    }
    __syncthreads();
}

__device__ __forceinline__ void l0_phase(
        const float* __restrict__ yg, unsigned short* __restrict__ og,
        const unsigned short* __restrict__ desc, const int* __restrict__ rowp,
        const float* __restrict__ dinv, const float* __restrict__ wf,
        int lane, int wv, int l, int nbg) {
    float w0 = wf[W0OFF + lane], b0 = wf[B0OFF + lane];
    for (int t = l; t < TILES; t += nbg) {
        int tb = t << 4;
        #pragma unroll
        for (int r = 0; r < 4; ++r) {
            int local = tb + (wv << 2) + r;
            int s = rowp[local], e = rowp[local + 1];
            float acc = 0.f;
            for (int i = s + lane; i < e; i += 64) acc += yg[desc[i]];
            #pragma unroll
            for (int off = 32; off; off >>= 1) acc += __shfl_xor(acc, off);
            float dv = dinv[local];
            float o = dv * tanh_fast(dv * acc * w0 + b0);
            og[((size_t)local << 6) + lane] = f2bf(o);
        }
    }
}

template<int FUSE>
__device__ __forceinline__ void heavy_phase(
        const unsigned short* __restrict__ hg, unsigned short* __restrict__ og,
        float* __restrict__ sg,
        const unsigned short* __restrict__ desc, const int* __restrict__ rowp,
        const float* __restrict__ dinv, const float* __restrict__ wf,
        const short8* __restrict__ frag, int mat, int boff,
        int lane, int wv, int l, int nbg, int tid,
        float* tile, float* dinvt, float (*pd)[16]) {
    const short8* fb = frag + (mat << 10);
    short8 Bh0 = fb[(wv << 8) +   0 + lane];
    short8 Bl0 = fb[(wv << 8) +  64 + lane];
    short8 Bh1 = fb[(wv << 8) + 128 + lane];
    short8 Bl1 = fb[(wv << 8) + 192 + lane];
    int mrow = lane & 15, quad = lane >> 4;
    float bias = wf[boff + (wv << 4) + mrow];
    float w4v = FUSE ? wf[W4OFF + (wv << 4) + mrow] : 0.f;

    for (int t = l; t < TILES; t += nbg) {
        int tb = t << 4;
        #pragma unroll
        for (int r = 0; r < 4; ++r) {
            int m = (wv << 2) + r;
            int local = tb + m;
            int s = rowp[local], e = rowp[local + 1];   // multiples of 16
            float acc = 0.f;
            for (int i = s; i < e; i += 16) {
                u16x8 d0 = *(const u16x8*)(desc + i);
                u16x8 d1 = *(const u16x8*)(desc + i + 8);
                unsigned short v[16];
                #pragma unroll
                for (int k = 0; k < 8; ++k) v[k]     = hg[(((unsigned)d0[k]) << 6) + lane];
                #pragma unroll
                for (int k = 0; k < 8; ++k) v[8 + k] = hg[(((unsigned)d1[k]) << 6) + lane];
                #pragma unroll
                for (int k = 0; k < 16; ++k) acc += bf2f(v[k]);
            }
            float dv = dinv[local];
            tile[m * 68 + lane] = acc * dv;
            if (lane == 0) dinvt[m] = dv;
        }
        __syncthreads();

        const float* arow = &tile[mrow * 68];
        float4 a0 = *(const float4*)(arow + (quad << 3));
        float4 a1 = *(const float4*)(arow + (quad << 3) + 4);
        float4 a2 = *(const float4*)(arow + 32 + (quad << 3));
        float4 a3 = *(const float4*)(arow + 32 + (quad << 3) + 4);
        float av0[8] = {a0.x, a0.y, a0.z, a0.w, a1.x, a1.y, a1.z, a1.w};
        float av1[8] = {a2.x, a2.y, a2.z, a2.w, a3.x, a3.y, a3.z, a3.w};
        short8 Ah0, Al0, Ah1, Al1;
        #pragma unroll
        for (int j = 0; j < 8; ++j) {
            unsigned short h0 = f2bf(av0[j]);
            Ah0[j] = (short)h0; Al0[j] = (short)f2bf(av0[j] - bf2f(h0));
            unsigned short h1 = f2bf(av1[j]);
            Ah1[j] = (short)h1; Al1[j] = (short)f2bf(av1[j] - bf2f(h1));
        }
        f32x4 c = {bias, bias, bias, bias};
        c = __builtin_amdgcn_mfma_f32_16x16x32_bf16(Ah0, Bh0, c, 0, 0, 0);
        c = __builtin_amdgcn_mfma_f32_16x16x32_bf16(Al0, Bh0, c, 0, 0, 0);
        c = __builtin_amdgcn_mfma_f32_16x16x32_bf16(Ah0, Bl0, c, 0, 0, 0);
        c = __builtin_amdgcn_mfma_f32_16x16x32_bf16(Ah1, Bh1, c, 0, 0, 0);
        c = __builtin_amdgcn_mfma_f32_16x16x32_bf16(Al1, Bh1, c, 0, 0, 0);
        c = __builtin_amdgcn_mfma_f32_16x16x32_bf16(Ah1, Bl1, c, 0, 0, 0);

        if (!FUSE) {
            #pragma unroll
            for (int r = 0; r < 4; ++r) {
                int m = (quad << 2) + r;
                og[((size_t)(tb + m) << 6) + (wv << 4) + mrow] = f2bf(dinvt[m] * tanh_fast(c[r]));
            }
            __syncthreads();                    // protect tile reuse across t-iterations
        } else {
            #pragma unroll
            for (int r = 0; r < 4; ++r) {
                float d = tanh_fast(c[r]) * w4v;
                d += __shfl_xor(d, 1); d += __shfl_xor(d, 2);
                d += __shfl_xor(d, 4); d += __shfl_xor(d, 8);
                if (mrow == 0) pd[wv][(quad << 2) + r] = d;
            }
            __syncthreads();
            if (tid < 16)
                sg[tb + tid] = dinvt[tid] * (pd[0][tid] + pd[1][tid] + pd[2][tid] + pd[3][tid]);
            __syncthreads();
        }
    }
}

__device__ __forceinline__ void prop_phase(
        const float* __restrict__ sg, const unsigned short* __restrict__ desc,
        const int* __restrict__ rowp, const float* __restrict__ dinv,
        const float* __restrict__ wf,
        float* yin, float* yb, float* kA, float* kB, float* kC,
        float c1, float c2, float c3, float c4, int stage, int fmode,
        void* out, int hidx, int g, int lane, int wv, int l, int nbg) {
    float b4 = wf[B4OFF];
    for (int t = l; t < TILES; t += nbg) {
        int tb = t << 4;
        #pragma unroll
        for (int r = 0; r < 4; ++r) {
            int local = tb + (wv << 2) + r;
            int s = rowp[local], e = rowp[local + 1];
            float acc = 0.f;
            for (int i = s + lane; i < e; i += 64) acc += sg[desc[i]];
            #pragma unroll
            for (int off = 32; off; off >>= 1) acc += __shfl_xor(acc, off);
            if (lane == 0) {
                int idx = g * PITCH + local;
                float dv = dinv[local];
                float k = dv * acc + b4;
                float ynew = yb[idx] + c1 * kA[idx] + c2 * kB[idx] + c3 * kC[idx] + c4 * k;
                if (stage == 0) kA[idx] = k;
                else if (stage == 1) kB[idx] = k;
                else if (stage == 2) kC[idx] = k;
                yin[idx] = dv * ynew;
                if (stage == 3) {
                    yb[idx] = ynew;
                    int cn = g * NNODE + local;
                    if (fmode) ((__hip_bfloat16*)out)[cn * HOR + hidx] = __float2bfloat16(ynew);
                    else       ((float*)out)[cn * HOR + hidx] = ynew;
                }
            }
        }
    }
}

__global__ __launch_bounds__(256, 4) void k_ode(
        unsigned short* hA, unsigned short* hB, float* yin, float* yb,
        float* kA, float* kB, float* kC, float* s4,
        const unsigned short* desc, const int* rowp, const float* dinv,
        const float* wf, const short8* frag, const int* modes, void* out,
        unsigned* bar) {
    __shared__ float tile[16 * 68];
    __shared__ float dinvt[16];
    __shared__ float pd[4][16];
    int tid = threadIdx.x, lane = tid & 63, wv = tid >> 6;
    int b = blockIdx.x, g = b & 7, l = b >> 3, nbg = gridDim.x >> 3;
    int fmode = modes[0];
    unsigned short* hAg = hA + ((size_t)g * PITCH << 6);
    unsigned short* hBg = hB + ((size_t)g * PITCH << 6);
    const float* ying = yin + g * PITCH;
    float* s4g = s4 + g * PITCH;
    unsigned be = 0;

    const float dt = 10.f / 9.f, dt3 = dt / 3.f;
    const float C1[4] = {0.f,  -dt3, dt,  dt * 0.125f};
    const float C2[4] = {0.f,  0.f,  -dt, dt * 0.375f};
    const float C3[4] = {0.f,  0.f,  0.f, dt * 0.375f};
    const float C4[4] = {dt3,  dt,   dt,  dt * 0.125f};

    for (int step = 0; step < NSTEP; ++step) {
        for (int st = 0; st < 4; ++st) {
            l0_phase(ying, hAg, desc, rowp, dinv, wf, lane, wv, l, nbg);
            ++be; graph_barrier(bar, g, be, nbg, tid);
            heavy_phase<0>(hAg, hBg, nullptr, desc, rowp, dinv, wf, frag, 0, B1OFF,
                           lane, wv, l, nbg, tid, tile, dinvt, pd);
            ++be; graph_barrier(bar, g, be, nbg, tid);
            heavy_phase<0>(hBg, hAg, nullptr, desc, rowp, dinv, wf, frag, 1, B2OFF,
                           lane, wv, l, nbg, tid, tile, dinvt, pd);
            ++be; graph_barrier(bar, g, be, nbg, tid);
            heavy_phase<1>(hAg, nullptr, s4g, desc, rowp, dinv, wf, frag, 2, B3OFF,
                           lane, wv, l, nbg, tid, tile, dinvt, pd);
            ++be; graph_barrier(bar, g, be, nbg, tid);
            prop_phase(s4g, desc, rowp, dinv, wf, yin, yb, kA, kB, kC,
                       C1[st], C2[st], C3[st], C4[st], st, fmode, out, step + 1,
                       g, lane, wv, l, nbg);
            ++be; graph_barrier(bar, g, be, nbg, tid);
        }
    }
}

// ================= host =================

extern "C" void kernel_launch(void* const* d_in, const int* in_sizes, int n_in,
                              void* d_out, int out_size, void* d_ws, size_t ws_size,
                              hipStream_t stream) {
    char* ws = (char*)d_ws;
    unsigned short* desc = (unsigned short*)(ws + OFF_DESC);
    unsigned short* hA   = (unsigned short*)(ws + OFF_HA);
    unsigned short* hB   = (unsigned short*)(ws + OFF_HB);
    float* yin  = (float*)(ws + OFF_YIN);
    float* yb   = (float*)(ws + OFF_YB);
    float* kA   = (float*)(ws + OFF_KA);
    float* kB   = (float*)(ws + OFF_KB);
    float* kC   = (float*)(ws + OFF_KC);
    float* s4   = (float*)(ws + OFF_S4);
    int*   deg  = (int*)(ws + OFF_DEG);
    int*   cur  = (int*)(ws + OFF_CUR);
    int*   rowp = (int*)(ws + OFF_ROWP);
    float* dinv = (float*)(ws + OFF_DINV);
    int*   modes= (int*)(ws + OFF_MODES);
    float* wf   = (float*)(ws + OFF_WF);
    short8* wfrag = (short8*)(ws + OFF_WFRAG);
    unsigned* bar = (unsigned*)(ws + OFF_BAR);

    const void* x    = d_in[0];
    const void* eidx = d_in[1];
    WPtrs wp;
    for (int i = 0; i < 10; ++i) wp.p[i] = d_in[2 + i];

    k_detect  <<<1, 64, 0, stream>>>(x, eidx, modes);
    k_init    <<<PITCH / 256, 256, 0, stream>>>(deg, bar);
    k_count   <<<EPG / 256, 256, 0, stream>>>(eidx, modes, deg);
    k_scan    <<<1, 256, 0, stream>>>(deg, rowp, cur, dinv);
    k_edgefill<<<(ECAP / 2 + 255) / 256, 256, 0, stream>>>((unsigned*)desc);
    k_scatter <<<(EPG + NNODE + 255) / 256, 256, 0, stream>>>(eidx, modes, cur, desc);
    k_convert <<<(WFTOT + 255) / 256, 256, 0, stream>>>(wp, wf, modes);
    k_mkfrag  <<<12, 256, 0, stream>>>(wf, wfrag);
    k_hpad    <<<96, 256, 0, stream>>>((unsigned*)hA, (unsigned*)hB);
    k_finalize<<<NG * PITCH / 256, 256, 0, stream>>>(dinv, x, modes, yin, yb, s4, d_out);

    // co-residency-validated persistent launch; 8 graphs x bpg blocks
    int nCU = 256, occ = 4;
    hipDeviceGetAttribute(&nCU, hipDeviceAttributeMultiprocessorCount, 0);
    hipOccupancyMaxActiveBlocksPerMultiprocessor(&occ, k_ode, 256, 0);
    if (occ < 1) occ = 1;
    int bpg = (occ * nCU) / 8;
    if (bpg > 128) bpg = 128;     // 125 tiles -> ~1 tile/block/phase
    if (bpg < 1) bpg = 1;
    int grid = bpg * 8;

    void* outp = d_out;
    void* args[] = { &hA, &hB, &yin, &yb, &kA, &kB, &kC, &s4,
                     &desc, &rowp, &dinv, &wf, &wfrag, &modes, &outp, &bar };
    hipLaunchCooperativeKernel((const void*)k_ode, dim3(grid), dim3(256), args, 0, stream);
}

// Round 7
// 2845.012 us; speedup vs baseline: 1.9155x; 1.8128x over previous
//
#include <hip/hip_runtime.h>
#include <hip/hip_bf16.h>

#define NNODE   2000
#define NG      8
#define EPG     64000
#define TSTEPS  24
#define HOR     10
#define NSTEP   (HOR-1)
#define PITCH   2048          // per-graph node pitch; row 2047 is the zero row
#define ECAP    98304         // padded CSR capacity (ushorts)
#define TILES   125           // 2000 / 16

// ---- workspace layout (bytes) ----
#define OFF_DESC    0
#define OFF_HA      196608
#define OFF_HB      2293760
#define OFF_YIN     4390912
#define OFF_YB      4456448
#define OFF_KA      4521984
#define OFF_KB      4587520
#define OFF_KC      4653056
#define OFF_S4      4718592
#define OFF_DEG     4784128
#define OFF_CUR     4792320
#define OFF_ROWP    4800512
#define OFF_DINV    4808960
#define OFF_MODES   4817152
#define OFF_WF      4817408
#define OFF_WFRAG   4868352
#define OFF_BAR     4917504
// total ~4.93 MB

#define W0OFF 0
#define B0OFF 64
#define W1OFF 128
#define B1OFF 4224
#define W2OFF 4288
#define B2OFF 8384
#define W3OFF 8448
#define B3OFF 12544
#define W4OFF 12608
#define B4OFF 12672
#define WFTOT 12673

typedef __attribute__((ext_vector_type(8))) short short8;
typedef __attribute__((ext_vector_type(8))) unsigned short u16x8;
typedef __attribute__((ext_vector_type(4))) float f32x4;

struct WPtrs { const void* p[10]; };

__device__ inline float tanh_fast(float x) {
    float xc = fminf(fmaxf(x, -15.f), 15.f);
    float e  = __expf(2.f * xc);
    return 1.f - 2.f / (e + 1.f);
}
__device__ inline unsigned short f2bf(float f) {
    unsigned u = __float_as_uint(f);
    u += 0x7fff + ((u >> 16) & 1);
    return (unsigned short)(u >> 16);
}
__device__ inline float bf2f(unsigned short h) {
    return __uint_as_float(((unsigned)h) << 16);
}
__device__ inline int ld_idx(const void* p, long i, int imode) {
    return imode ? (int)((const long long*)p)[i] : ((const int*)p)[i];
}

// ================= setup kernels (R4-proven) =================

__global__ void k_detect(const void* x, const void* eidx, int* modes) {
    int lane = threadIdx.x;
    const unsigned* xw = (const unsigned*)x;
    unsigned w = xw[lane];
    int ex = (w >> 7) & 0xFF;
    unsigned long long m = __ballot(ex >= 100 && ex <= 145);
    const unsigned* ew = (const unsigned*)eidx;
    unsigned long long m2 = __ballot(ew[2*lane + 1] != 0);
    if (lane == 0) {
        modes[0] = (__popcll(m) >= 48) ? 1 : 0;
        modes[1] = (__popcll(m2) == 0) ? 1 : 0;
    }
}

__global__ void k_init(int* deg, unsigned* bar) {
    int n = blockIdx.x * 256 + threadIdx.x;
    if (n < PITCH) deg[n] = (n < NNODE) ? 1 : 0;
    if (n < NG * 256) bar[n] = 0;
}

__global__ void k_count(const void* eidx, const int* __restrict__ modes, int* deg) {
    int e = blockIdx.x * 256 + threadIdx.x;
    int imode = modes[1];
    int dst = ld_idx(eidx, (long)EPG + e, imode);
    atomicAdd(&deg[dst], 1);
}

__global__ __launch_bounds__(256) void k_scan(const int* __restrict__ deg, int* rowp,
                                              int* cursor, float* dinv) {
    __shared__ int part[256];
    int t = threadIdx.x, base = t * 8;
    int loc[8]; int s = 0;
    #pragma unroll
    for (int k = 0; k < 8; ++k) {
        int d = deg[base + k];
        int p = (d + 15) & ~15;
        loc[k] = p; s += p;
    }
    part[t] = s; __syncthreads();
    for (int off = 1; off < 256; off <<= 1) {
        int v = (t >= off) ? part[t - off] : 0;
        __syncthreads();
        part[t] += v;
        __syncthreads();
    }
    int run = part[t] - s;
    #pragma unroll
    for (int k = 0; k < 8; ++k) {
        rowp[base + k] = run; cursor[base + k] = run;
        int d = deg[base + k];
        dinv[base + k] = (d > 0) ? rsqrtf((float)d) : 0.f;
        run += loc[k];
    }
    if (t == 255) rowp[PITCH] = part[255];
}

__global__ void k_edgefill(unsigned* desc32) {
    int i = blockIdx.x * 256 + threadIdx.x;
    if (i < ECAP / 2) desc32[i] = 0x07FF07FFu;     // sentinel -> zero row 2047
}

__global__ void k_scatter(const void* eidx, const int* __restrict__ modes,
                          int* cursor, unsigned short* desc) {
    int idx = blockIdx.x * 256 + threadIdx.x;
    if (idx >= EPG + NNODE) return;
    int imode = modes[1];
    int s, d;
    if (idx < EPG) { s = ld_idx(eidx, idx, imode); d = ld_idx(eidx, (long)EPG + idx, imode); }
    else           { s = idx - EPG; d = s; }
    int pos = atomicAdd(&cursor[d], 1);
    desc[pos] = (unsigned short)s;
}

__global__ void k_convert(WPtrs wp, float* wf, const int* __restrict__ modes) {
    int idx = blockIdx.x * 256 + threadIdx.x;
    if (idx >= WFTOT) return;
    int fmode = modes[0];
    const int offs[10]  = {W0OFF,B0OFF,W1OFF,B1OFF,W2OFF,B2OFF,W3OFF,B3OFF,W4OFF,B4OFF};
    const int sizes[10] = {64,64,4096,64,4096,64,4096,64,64,1};
    #pragma unroll
    for (int s = 0; s < 10; ++s) {
        if (idx >= offs[s] && idx < offs[s] + sizes[s]) {
            int j = idx - offs[s];
            wf[idx] = fmode ? __bfloat162float(((const __hip_bfloat16*)wp.p[s])[j])
                            : ((const float*)wp.p[s])[j];
        }
    }
}

__global__ void k_mkfrag(const float* __restrict__ wf, short8* frag) {
    int t = blockIdx.x * 256 + threadIdx.x;
    if (t >= 3072) return;
    int lane = t & 63, half = (t >> 6) & 1, kh = (t >> 7) & 1, nb = (t >> 8) & 3, mat = t >> 10;
    const int woffs[3] = {W1OFF, W2OFF, W3OFF};
    const float* W = wf + woffs[mat];
    int n  = nb * 16 + (lane & 15);
    int k0 = kh * 32 + (lane >> 4) * 8;
    short8 v;
    #pragma unroll
    for (int j = 0; j < 8; ++j) {
        float w = W[(k0 + j) * 64 + n];
        unsigned short h = f2bf(w);
        v[j] = half ? (short)f2bf(w - bf2f(h)) : (short)h;
    }
    frag[t] = v;
}

__global__ void k_hpad(unsigned* hA32, unsigned* hB32) {
    int idx = blockIdx.x * 256 + threadIdx.x;
    if (idx >= 2 * NG * 48 * 32) return;
    int b = idx / (NG * 48 * 32), r = idx % (NG * 48 * 32);
    int g = r / (48 * 32), rr = r % (48 * 32);
    int row = NNODE + rr / 32, fp = rr % 32;
    unsigned* p = b ? hB32 : hA32;
    p[(g * PITCH + row) * 32 + fp] = 0;
}

__global__ void k_finalize(const float* __restrict__ dinv, const void* x,
                           const int* __restrict__ modes,
                           float* yin, float* yb, float* s4, void* out) {
    int idx = blockIdx.x * 256 + threadIdx.x;
    if (idx >= NG * PITCH) return;
    int g = idx >> 11, local = idx & (PITCH - 1);
    if (local >= NNODE) { yin[idx] = 0.f; yb[idx] = 0.f; s4[idx] = 0.f; return; }
    int cn = g * NNODE + local;
    float y0 = modes[0] ? __bfloat162float(((const __hip_bfloat16*)x)[cn * TSTEPS + (TSTEPS - 1)])
                        : ((const float*)x)[cn * TSTEPS + (TSTEPS - 1)];
    yin[idx] = dinv[local] * y0;
    yb[idx]  = y0;
    if (modes[0]) ((__hip_bfloat16*)out)[cn * HOR] = __float2bfloat16(y0);
    else          ((float*)out)[cn * HOR] = y0;
}

// ---- initial layer 0 (runs once per launch; normal loads; R4-proven) ----
__global__ __launch_bounds__(256) void k_layer0(
        const float* __restrict__ yin, unsigned short* __restrict__ hout,
        const unsigned short* __restrict__ desc, const int* __restrict__ rowp,
        const float* __restrict__ dinv, const float* __restrict__ wf) {
    int lane = threadIdx.x & 63, wv = threadIdx.x >> 6;
    int b = blockIdx.x;
    int g = b & 7, local = (b >> 3) * 4 + wv;
    const float* yg = yin + g * PITCH;
    int s = rowp[local], e = rowp[local + 1];
    float acc = 0.f;
    for (int i = s + lane; i < e; i += 64) acc += yg[desc[i]];
    #pragma unroll
    for (int off = 32; off; off >>= 1) acc += __shfl_xor(acc, off);
    float dv = dinv[local];
    float o = dv * tanh_fast(dv * acc * wf[W0OFF + lane] + wf[B0OFF + lane]);
    hout[((g * PITCH + local) << 6) + lane] = f2bf(o);
}

// ---- heavy layers (R4-proven, unchanged) ----
template<int FUSE>
__global__ __launch_bounds__(256, 4) void k_layer(
        const unsigned short* __restrict__ hin, unsigned short* __restrict__ hout,
        float* __restrict__ s4,
        const unsigned short* __restrict__ desc, const int* __restrict__ rowp,
        const float* __restrict__ dinv, const float* __restrict__ wf,
        const short8* __restrict__ frag, int mat, int boff) {
    __shared__ float tile[16 * 68];
    __shared__ float dinvt[16];
    __shared__ float pd[4][16];
    int lane = threadIdx.x & 63, wv = threadIdx.x >> 6;
    int b = blockIdx.x;
    int g = b & 7, tb = (b >> 3) << 4;
    const unsigned short* hg = hin + ((size_t)g * PITCH << 6);

    const short8* fb = frag + (mat << 10);
    short8 Bh0 = fb[(wv << 8) +   0 + lane];
    short8 Bl0 = fb[(wv << 8) +  64 + lane];
    short8 Bh1 = fb[(wv << 8) + 128 + lane];
    short8 Bl1 = fb[(wv << 8) + 192 + lane];

    #pragma unroll
    for (int r = 0; r < 4; ++r) {
        int m = (wv << 2) + r;
        int local = tb + m;
        int s = rowp[local], e = rowp[local + 1];
        float acc = 0.f;
        for (int i = s; i < e; i += 16) {
            u16x8 d0 = *(const u16x8*)(desc + i);
            u16x8 d1 = *(const u16x8*)(desc + i + 8);
            unsigned short v[16];
            #pragma unroll
            for (int k = 0; k < 8; ++k) v[k]     = hg[(((unsigned)d0[k]) << 6) + lane];
            #pragma unroll
            for (int k = 0; k < 8; ++k) v[8 + k] = hg[(((unsigned)d1[k]) << 6) + lane];
            #pragma unroll
            for (int k = 0; k < 16; ++k) acc += bf2f(v[k]);
        }
        float dv = dinv[local];
        tile[m * 68 + lane] = acc * dv;
        if (lane == 0) dinvt[m] = dv;
    }
    __syncthreads();

    int mrow = lane & 15, quad = lane >> 4;
    const float* arow = &tile[mrow * 68];
    float4 a0 = *(const float4*)(arow + (quad << 3));
    float4 a1 = *(const float4*)(arow + (quad << 3) + 4);
    float4 a2 = *(const float4*)(arow + 32 + (quad << 3));
    float4 a3 = *(const float4*)(arow + 32 + (quad << 3) + 4);
    float av0[8] = {a0.x, a0.y, a0.z, a0.w, a1.x, a1.y, a1.z, a1.w};
    float av1[8] = {a2.x, a2.y, a2.z, a2.w, a3.x, a3.y, a3.z, a3.w};
    short8 Ah0, Al0, Ah1, Al1;
    #pragma unroll
    for (int j = 0; j < 8; ++j) {
        unsigned short h0 = f2bf(av0[j]);
        Ah0[j] = (short)h0; Al0[j] = (short)f2bf(av0[j] - bf2f(h0));
        unsigned short h1 = f2bf(av1[j]);
        Ah1[j] = (short)h1; Al1[j] = (short)f2bf(av1[j] - bf2f(h1));
    }
    float bias = wf[boff + (wv << 4) + mrow];
    f32x4 c = {bias, bias, bias, bias};
    c = __builtin_amdgcn_mfma_f32_16x16x32_bf16(Ah0, Bh0, c, 0, 0, 0);
    c = __builtin_amdgcn_mfma_f32_16x16x32_bf16(Al0, Bh0, c, 0, 0, 0);
    c = __builtin_amdgcn_mfma_f32_16x16x32_bf16(Ah0, Bl0, c, 0, 0, 0);
    c = __builtin_amdgcn_mfma_f32_16x16x32_bf16(Ah1, Bh1, c, 0, 0, 0);
    c = __builtin_amdgcn_mfma_f32_16x16x32_bf16(Al1, Bh1, c, 0, 0, 0);
    c = __builtin_amdgcn_mfma_f32_16x16x32_bf16(Ah1, Bl1, c, 0, 0, 0);

    if (!FUSE) {
        #pragma unroll
        for (int r = 0; r < 4; ++r) {
            int m = (quad << 2) + r;
            hout[(((size_t)g * PITCH + tb + m) << 6) + (wv << 4) + mrow] = f2bf(dinvt[m] * tanh_fast(c[r]));
        }
    } else {
        float w4v = wf[W4OFF + (wv << 4) + mrow];
        #pragma unroll
        for (int r = 0; r < 4; ++r) {
            float d = tanh_fast(c[r]) * w4v;
            d += __shfl_xor(d, 1); d += __shfl_xor(d, 2);
            d += __shfl_xor(d, 4); d += __shfl_xor(d, 8);
            if (mrow == 0) pd[wv][(quad << 2) + r] = d;
        }
        __syncthreads();
        if (threadIdx.x < 16)
            s4[g * PITCH + tb + threadIdx.x] = dinvt[threadIdx.x] *
                (pd[0][threadIdx.x] + pd[1][threadIdx.x] + pd[2][threadIdx.x] + pd[3][threadIdx.x]);
    }
}

// ---- fused prop(st) + layer0(st+1): fence-free in-kernel per-graph barrier ----
// Cross-block array inside this kernel is ONLY yin (ŷ): accessed exclusively via
// relaxed agent-scope 4B atomics (LLC coherence point, never L2-cached), so the
// barrier needs NO buffer_wbl2/buffer_inv — the per-block cache ops that made
// R5/R6 cost ~43 µs/barrier. Release = the vmcnt(0) drain __syncthreads already
// does; acquire = nothing (desc/rowp/wf stale-cache-safe: immutable).
__global__ __launch_bounds__(256) void k_bridge(
        const float* __restrict__ s4, float* yin, float* __restrict__ yb,
        float* __restrict__ kA, float* __restrict__ kB, float* __restrict__ kC,
        const unsigned short* __restrict__ desc, const int* __restrict__ rowp,
        const float* __restrict__ dinv, const float* __restrict__ wf,
        unsigned short* __restrict__ hout, const int* __restrict__ modes, void* out,
        float c1, float c2, float c3, float c4, int stage, int hidx,
        unsigned be, unsigned* bar) {
    int tid = threadIdx.x, lane = tid & 63, wv = tid >> 6;
    int b = blockIdx.x, g = b & 7, l = b >> 3;
    unsigned nbg = gridDim.x >> 3;
    const float* sg = s4 + g * PITCH;
    float* yg = yin + g * PITCH;
    float b4 = wf[B4OFF];
    int fmode = modes[0];

    // ---- phase A: prop (k, y_next, ŷ) ----
    for (int t = l; t < TILES; t += nbg) {
        #pragma unroll
        for (int r = 0; r < 4; ++r) {
            int local = (t << 4) + (wv << 2) + r;
            int s = rowp[local], e = rowp[local + 1];
            float acc = 0.f;
            for (int i = s + lane; i < e; i += 64) acc += sg[desc[i]];
            #pragma unroll
            for (int off = 32; off; off >>= 1) acc += __shfl_xor(acc, off);
            if (lane == 0) {
                int idx = g * PITCH + local;
                float dv = dinv[local];
                float k = dv * acc + b4;
                float ynew = yb[idx] + c1 * kA[idx] + c2 * kB[idx] + c3 * kC[idx] + c4 * k;
                if (stage == 0) kA[idx] = k;
                else if (stage == 1) kB[idx] = k;
                else if (stage == 2) kC[idx] = k;
                __hip_atomic_store(&yin[idx], dv * ynew, __ATOMIC_RELAXED, __HIP_MEMORY_SCOPE_AGENT);
                if (stage == 3) {
                    yb[idx] = ynew;
                    int cn = g * NNODE + local;
                    if (fmode) ((__hip_bfloat16*)out)[cn * HOR + hidx] = __float2bfloat16(ynew);
                    else       ((float*)out)[cn * HOR + hidx] = ynew;
                }
            }
        }
    }

    // ---- fence-free per-graph barrier (monotone epoch, relaxed atomics only) ----
    __syncthreads();                               // drains each wave's vmcnt -> ŷ at LLC
    if (tid == 0) {
        unsigned* cnt = bar + (g << 8);
        unsigned* ep  = bar + (g << 8) + 64;
        if (__hip_atomic_fetch_add(cnt, 1u, __ATOMIC_RELAXED, __HIP_MEMORY_SCOPE_AGENT) + 1u == be * nbg)
            __hip_atomic_store(ep, be, __ATOMIC_RELAXED, __HIP_MEMORY_SCOPE_AGENT);
        while (__hip_atomic_load(ep, __ATOMIC_RELAXED, __HIP_MEMORY_SCOPE_AGENT) < be)
            __builtin_amdgcn_s_sleep(2);
        asm volatile("" ::: "memory");             // compiler-only ordering fence
    }
    __syncthreads();

    // ---- phase B: layer0 (gather ŷ via LLC-coherent loads, write h0) ----
    float w0 = wf[W0OFF + lane], b0 = wf[B0OFF + lane];
    for (int t = l; t < TILES; t += nbg) {
        #pragma unroll
        for (int r = 0; r < 4; ++r) {
            int local = (t << 4) + (wv << 2) + r;
            int s = rowp[local], e = rowp[local + 1];
            float acc = 0.f;
            for (int i = s + lane; i < e; i += 64)
                acc += __hip_atomic_load(&yg[desc[i]], __ATOMIC_RELAXED, __HIP_MEMORY_SCOPE_AGENT);
            #pragma unroll
            for (int off = 32; off; off >>= 1) acc += __shfl_xor(acc, off);
            float dv = dinv[local];
            float o = dv * tanh_fast(dv * acc * w0 + b0);
            hout[((size_t)(g * PITCH + local) << 6) + lane] = f2bf(o);
        }
    }
}

// ================= host =================

extern "C" void kernel_launch(void* const* d_in, const int* in_sizes, int n_in,
                              void* d_out, int out_size, void* d_ws, size_t ws_size,
                              hipStream_t stream) {
    char* ws = (char*)d_ws;
    unsigned short* desc = (unsigned short*)(ws + OFF_DESC);
    unsigned short* hA   = (unsigned short*)(ws + OFF_HA);
    unsigned short* hB   = (unsigned short*)(ws + OFF_HB);
    float* yin  = (float*)(ws + OFF_YIN);
    float* yb   = (float*)(ws + OFF_YB);
    float* kA   = (float*)(ws + OFF_KA);
    float* kB   = (float*)(ws + OFF_KB);
    float* kC   = (float*)(ws + OFF_KC);
    float* s4   = (float*)(ws + OFF_S4);
    int*   deg  = (int*)(ws + OFF_DEG);
    int*   cur  = (int*)(ws + OFF_CUR);
    int*   rowp = (int*)(ws + OFF_ROWP);
    float* dinv = (float*)(ws + OFF_DINV);
    int*   modes= (int*)(ws + OFF_MODES);
    float* wf   = (float*)(ws + OFF_WF);
    short8* wfrag = (short8*)(ws + OFF_WFRAG);
    unsigned* bar = (unsigned*)(ws + OFF_BAR);

    const void* x    = d_in[0];
    const void* eidx = d_in[1];
    WPtrs wp;
    for (int i = 0; i < 10; ++i) wp.p[i] = d_in[2 + i];

    k_detect  <<<1, 64, 0, stream>>>(x, eidx, modes);
    k_init    <<<PITCH / 256, 256, 0, stream>>>(deg, bar);
    k_count   <<<EPG / 256, 256, 0, stream>>>(eidx, modes, deg);
    k_scan    <<<1, 256, 0, stream>>>(deg, rowp, cur, dinv);
    k_edgefill<<<(ECAP / 2 + 255) / 256, 256, 0, stream>>>((unsigned*)desc);
    k_scatter <<<(EPG + NNODE + 255) / 256, 256, 0, stream>>>(eidx, modes, cur, desc);
    k_convert <<<(WFTOT + 255) / 256, 256, 0, stream>>>(wp, wf, modes);
    k_mkfrag  <<<12, 256, 0, stream>>>(wf, wfrag);
    k_hpad    <<<96, 256, 0, stream>>>((unsigned*)hA, (unsigned*)hB);
    k_finalize<<<NG * PITCH / 256, 256, 0, stream>>>(dinv, x, modes, yin, yb, s4, d_out);

    // bridge co-residency sizing
    int nCU = 256, occB = 8;
    hipDeviceGetAttribute(&nCU, hipDeviceAttributeMultiprocessorCount, 0);
    hipOccupancyMaxActiveBlocksPerMultiprocessor(&occB, k_bridge, 256, 0);
    if (occB < 1) occB = 1;
    int bpg = (occB * nCU) / 8;
    if (bpg > TILES) bpg = TILES;
    if (bpg < 1) bpg = 1;
    int gridB = bpg * 8;

    const float dt = 10.f / 9.f, dt3 = dt / 3.f;
    const float C1[4] = {0.f,  -dt3, dt,  dt * 0.125f};
    const float C2[4] = {0.f,  0.f,  -dt, dt * 0.375f};
    const float C3[4] = {0.f,  0.f,  0.f, dt * 0.375f};
    const float C4[4] = {dt3,  dt,   dt,  dt * 0.125f};

    k_layer0<<<4000, 256, 0, stream>>>(yin, hA, desc, rowp, dinv, wf);  // initial

    unsigned be = 0;
    for (int step = 0; step < NSTEP; ++step) {
        for (int st = 0; st < 4; ++st) {
            k_layer<0><<<1000, 256, 0, stream>>>(hA, hB, nullptr, desc, rowp, dinv, wf, wfrag, 0, B1OFF);
            k_layer<0><<<1000, 256, 0, stream>>>(hB, hA, nullptr, desc, rowp, dinv, wf, wfrag, 1, B2OFF);
            k_layer<1><<<1000, 256, 0, stream>>>(hA, nullptr, s4, desc, rowp, dinv, wf, wfrag, 2, B3OFF);
            ++be;
            float c1 = C1[st], c2 = C2[st], c3 = C3[st], c4 = C4[st];
            int stage = st, hidx = step + 1;
            void* outp = d_out;
            void* args[] = { &s4, &yin, &yb, &kA, &kB, &kC, &desc, &rowp, &dinv, &wf,
                             &hA, &modes, &outp, &c1, &c2, &c3, &c4, &stage, &hidx, &be, &bar };
            hipLaunchCooperativeKernel((const void*)k_bridge, dim3(gridB), dim3(256),
                                       args, 0, stream);
        }
    }
}

// Round 8
// 1931.474 us; speedup vs baseline: 2.8215x; 1.4730x over previous
//
#include <hip/hip_runtime.h>
#include <hip/hip_bf16.h>

#define NNODE   2000
#define NG      8
#define EPG     64000
#define TSTEPS  24
#define HOR     10
#define NSTEP   (HOR-1)
#define PITCH   2048          // per-graph node pitch; row 2047 is the zero row
#define ECAP    98304         // padded CSR capacity (ushorts)
#define TILES   125           // 2000 / 16

// ---- workspace layout (bytes) ----
#define OFF_DESC    0
#define OFF_HA      196608
#define OFF_HB      2293760
#define OFF_YIN     4390912
#define OFF_YB      4456448
#define OFF_KA      4521984
#define OFF_KB      4587520
#define OFF_KC      4653056
#define OFF_S4      4718592
#define OFF_DEG     4784128
#define OFF_CUR     4792320
#define OFF_ROWP    4800512
#define OFF_DINV    4808960
#define OFF_MODES   4817152
#define OFF_WF      4817408
#define OFF_WFRAG   4868352
#define OFF_BAR     4917504
// total ~4.93 MB

#define W0OFF 0
#define B0OFF 64
#define W1OFF 128
#define B1OFF 4224
#define W2OFF 4288
#define B2OFF 8384
#define W3OFF 8448
#define B3OFF 12544
#define W4OFF 12608
#define B4OFF 12672
#define WFTOT 12673

typedef __attribute__((ext_vector_type(8))) short short8;
typedef __attribute__((ext_vector_type(8))) unsigned short u16x8;
typedef __attribute__((ext_vector_type(4))) float f32x4;

struct WPtrs { const void* p[10]; };

__device__ inline float tanh_fast(float x) {
    float xc = fminf(fmaxf(x, -15.f), 15.f);
    float e  = __expf(2.f * xc);
    return 1.f - 2.f / (e + 1.f);
}
__device__ inline unsigned short f2bf(float f) {
    unsigned u = __float_as_uint(f);
    u += 0x7fff + ((u >> 16) & 1);
    return (unsigned short)(u >> 16);
}
__device__ inline float bf2f(unsigned short h) {
    return __uint_as_float(((unsigned)h) << 16);
}
__device__ inline int ld_idx(const void* p, long i, int imode) {
    return imode ? (int)((const long long*)p)[i] : ((const int*)p)[i];
}

// ================= setup kernels (R4-proven) =================

__global__ void k_detect(const void* x, const void* eidx, int* modes) {
    int lane = threadIdx.x;
    const unsigned* xw = (const unsigned*)x;
    unsigned w = xw[lane];
    int ex = (w >> 7) & 0xFF;
    unsigned long long m = __ballot(ex >= 100 && ex <= 145);
    const unsigned* ew = (const unsigned*)eidx;
    unsigned long long m2 = __ballot(ew[2*lane + 1] != 0);
    if (lane == 0) {
        modes[0] = (__popcll(m) >= 48) ? 1 : 0;
        modes[1] = (__popcll(m2) == 0) ? 1 : 0;
    }
}

__global__ void k_init(int* deg, unsigned* bar) {
    int n = blockIdx.x * 256 + threadIdx.x;
    if (n < PITCH) deg[n] = (n < NNODE) ? 1 : 0;
    if (n < NG * 256) bar[n] = 0;
}

__global__ void k_count(const void* eidx, const int* __restrict__ modes, int* deg) {
    int e = blockIdx.x * 256 + threadIdx.x;
    int imode = modes[1];
    int dst = ld_idx(eidx, (long)EPG + e, imode);
    atomicAdd(&deg[dst], 1);
}

__global__ __launch_bounds__(256) void k_scan(const int* __restrict__ deg, int* rowp,
                                              int* cursor, float* dinv) {
    __shared__ int part[256];
    int t = threadIdx.x, base = t * 8;
    int loc[8]; int s = 0;
    #pragma unroll
    for (int k = 0; k < 8; ++k) {
        int d = deg[base + k];
        int p = (d + 15) & ~15;
        loc[k] = p; s += p;
    }
    part[t] = s; __syncthreads();
    for (int off = 1; off < 256; off <<= 1) {
        int v = (t >= off) ? part[t - off] : 0;
        __syncthreads();
        part[t] += v;
        __syncthreads();
    }
    int run = part[t] - s;
    #pragma unroll
    for (int k = 0; k < 8; ++k) {
        rowp[base + k] = run; cursor[base + k] = run;
        int d = deg[base + k];
        dinv[base + k] = (d > 0) ? rsqrtf((float)d) : 0.f;
        run += loc[k];
    }
    if (t == 255) rowp[PITCH] = part[255];
}

__global__ void k_edgefill(unsigned* desc32) {
    int i = blockIdx.x * 256 + threadIdx.x;
    if (i < ECAP / 2) desc32[i] = 0x07FF07FFu;     // sentinel -> zero row 2047
}

__global__ void k_scatter(const void* eidx, const int* __restrict__ modes,
                          int* cursor, unsigned short* desc) {
    int idx = blockIdx.x * 256 + threadIdx.x;
    if (idx >= EPG + NNODE) return;
    int imode = modes[1];
    int s, d;
    if (idx < EPG) { s = ld_idx(eidx, idx, imode); d = ld_idx(eidx, (long)EPG + idx, imode); }
    else           { s = idx - EPG; d = s; }
    int pos = atomicAdd(&cursor[d], 1);
    desc[pos] = (unsigned short)s;
}

__global__ void k_convert(WPtrs wp, float* wf, const int* __restrict__ modes) {
    int idx = blockIdx.x * 256 + threadIdx.x;
    if (idx >= WFTOT) return;
    int fmode = modes[0];
    const int offs[10]  = {W0OFF,B0OFF,W1OFF,B1OFF,W2OFF,B2OFF,W3OFF,B3OFF,W4OFF,B4OFF};
    const int sizes[10] = {64,64,4096,64,4096,64,4096,64,64,1};
    #pragma unroll
    for (int s = 0; s < 10; ++s) {
        if (idx >= offs[s] && idx < offs[s] + sizes[s]) {
            int j = idx - offs[s];
            wf[idx] = fmode ? __bfloat162float(((const __hip_bfloat16*)wp.p[s])[j])
                            : ((const float*)wp.p[s])[j];
        }
    }
}

__global__ void k_mkfrag(const float* __restrict__ wf, short8* frag) {
    int t = blockIdx.x * 256 + threadIdx.x;
    if (t >= 3072) return;
    int lane = t & 63, half = (t >> 6) & 1, kh = (t >> 7) & 1, nb = (t >> 8) & 3, mat = t >> 10;
    const int woffs[3] = {W1OFF, W2OFF, W3OFF};
    const float* W = wf + woffs[mat];
    int n  = nb * 16 + (lane & 15);
    int k0 = kh * 32 + (lane >> 4) * 8;
    short8 v;
    #pragma unroll
    for (int j = 0; j < 8; ++j) {
        float w = W[(k0 + j) * 64 + n];
        unsigned short h = f2bf(w);
        v[j] = half ? (short)f2bf(w - bf2f(h)) : (short)h;
    }
    frag[t] = v;
}

__global__ void k_hpad(unsigned* hA32, unsigned* hB32) {
    int idx = blockIdx.x * 256 + threadIdx.x;
    if (idx >= 2 * NG * 48 * 32) return;
    int b = idx / (NG * 48 * 32), r = idx % (NG * 48 * 32);
    int g = r / (48 * 32), rr = r % (48 * 32);
    int row = NNODE + rr / 32, fp = rr % 32;
    unsigned* p = b ? hB32 : hA32;
    p[(g * PITCH + row) * 32 + fp] = 0;
}

__global__ void k_finalize(const float* __restrict__ dinv, const void* x,
                           const int* __restrict__ modes,
                           float* yin, float* yb, float* s4, void* out) {
    int idx = blockIdx.x * 256 + threadIdx.x;
    if (idx >= NG * PITCH) return;
    int g = idx >> 11, local = idx & (PITCH - 1);
    if (local >= NNODE) { yin[idx] = 0.f; yb[idx] = 0.f; s4[idx] = 0.f; return; }
    int cn = g * NNODE + local;
    float y0 = modes[0] ? __bfloat162float(((const __hip_bfloat16*)x)[cn * TSTEPS + (TSTEPS - 1)])
                        : ((const float*)x)[cn * TSTEPS + (TSTEPS - 1)];
    yin[idx] = dinv[local] * y0;
    yb[idx]  = y0;
    if (modes[0]) ((__hip_bfloat16*)out)[cn * HOR] = __float2bfloat16(y0);
    else          ((float*)out)[cn * HOR] = y0;
}

// ---- initial layer 0 (runs once per launch; normal loads; R4-proven) ----
__global__ __launch_bounds__(256) void k_layer0(
        const float* __restrict__ yin, unsigned short* __restrict__ hout,
        const unsigned short* __restrict__ desc, const int* __restrict__ rowp,
        const float* __restrict__ dinv, const float* __restrict__ wf) {
    int lane = threadIdx.x & 63, wv = threadIdx.x >> 6;
    int b = blockIdx.x;
    int g = b & 7, local = (b >> 3) * 4 + wv;
    const float* yg = yin + g * PITCH;
    int s = rowp[local], e = rowp[local + 1];
    float acc = 0.f;
    for (int i = s + lane; i < e; i += 64) acc += yg[desc[i]];
    #pragma unroll
    for (int off = 32; off; off >>= 1) acc += __shfl_xor(acc, off);
    float dv = dinv[local];
    float o = dv * tanh_fast(dv * acc * wf[W0OFF + lane] + wf[B0OFF + lane]);
    hout[((g * PITCH + local) << 6) + lane] = f2bf(o);
}

// ---- heavy layers (R4-proven, unchanged) ----
template<int FUSE>
__global__ __launch_bounds__(256, 4) void k_layer(
        const unsigned short* __restrict__ hin, unsigned short* __restrict__ hout,
        float* __restrict__ s4,
        const unsigned short* __restrict__ desc, const int* __restrict__ rowp,
        const float* __restrict__ dinv, const float* __restrict__ wf,
        const short8* __restrict__ frag, int mat, int boff) {
    __shared__ float tile[16 * 68];
    __shared__ float dinvt[16];
    __shared__ float pd[4][16];
    int lane = threadIdx.x & 63, wv = threadIdx.x >> 6;
    int b = blockIdx.x;
    int g = b & 7, tb = (b >> 3) << 4;
    const unsigned short* hg = hin + ((size_t)g * PITCH << 6);

    const short8* fb = frag + (mat << 10);
    short8 Bh0 = fb[(wv << 8) +   0 + lane];
    short8 Bl0 = fb[(wv << 8) +  64 + lane];
    short8 Bh1 = fb[(wv << 8) + 128 + lane];
    short8 Bl1 = fb[(wv << 8) + 192 + lane];

    #pragma unroll
    for (int r = 0; r < 4; ++r) {
        int m = (wv << 2) + r;
        int local = tb + m;
        int s = rowp[local], e = rowp[local + 1];
        float acc = 0.f;
        for (int i = s; i < e; i += 16) {
            u16x8 d0 = *(const u16x8*)(desc + i);
            u16x8 d1 = *(const u16x8*)(desc + i + 8);
            unsigned short v[16];
            #pragma unroll
            for (int k = 0; k < 8; ++k) v[k]     = hg[(((unsigned)d0[k]) << 6) + lane];
            #pragma unroll
            for (int k = 0; k < 8; ++k) v[8 + k] = hg[(((unsigned)d1[k]) << 6) + lane];
            #pragma unroll
            for (int k = 0; k < 16; ++k) acc += bf2f(v[k]);
        }
        float dv = dinv[local];
        tile[m * 68 + lane] = acc * dv;
        if (lane == 0) dinvt[m] = dv;
    }
    __syncthreads();

    int mrow = lane & 15, quad = lane >> 4;
    const float* arow = &tile[mrow * 68];
    float4 a0 = *(const float4*)(arow + (quad << 3));
    float4 a1 = *(const float4*)(arow + (quad << 3) + 4);
    float4 a2 = *(const float4*)(arow + 32 + (quad << 3));
    float4 a3 = *(const float4*)(arow + 32 + (quad << 3) + 4);
    float av0[8] = {a0.x, a0.y, a0.z, a0.w, a1.x, a1.y, a1.z, a1.w};
    float av1[8] = {a2.x, a2.y, a2.z, a2.w, a3.x, a3.y, a3.z, a3.w};
    short8 Ah0, Al0, Ah1, Al1;
    #pragma unroll
    for (int j = 0; j < 8; ++j) {
        unsigned short h0 = f2bf(av0[j]);
        Ah0[j] = (short)h0; Al0[j] = (short)f2bf(av0[j] - bf2f(h0));
        unsigned short h1 = f2bf(av1[j]);
        Ah1[j] = (short)h1; Al1[j] = (short)f2bf(av1[j] - bf2f(h1));
    }
    float bias = wf[boff + (wv << 4) + mrow];
    f32x4 c = {bias, bias, bias, bias};
    c = __builtin_amdgcn_mfma_f32_16x16x32_bf16(Ah0, Bh0, c, 0, 0, 0);
    c = __builtin_amdgcn_mfma_f32_16x16x32_bf16(Al0, Bh0, c, 0, 0, 0);
    c = __builtin_amdgcn_mfma_f32_16x16x32_bf16(Ah0, Bl0, c, 0, 0, 0);
    c = __builtin_amdgcn_mfma_f32_16x16x32_bf16(Ah1, Bh1, c, 0, 0, 0);
    c = __builtin_amdgcn_mfma_f32_16x16x32_bf16(Al1, Bh1, c, 0, 0, 0);
    c = __builtin_amdgcn_mfma_f32_16x16x32_bf16(Ah1, Bl1, c, 0, 0, 0);

    if (!FUSE) {
        #pragma unroll
        for (int r = 0; r < 4; ++r) {
            int m = (quad << 2) + r;
            hout[(((size_t)g * PITCH + tb + m) << 6) + (wv << 4) + mrow] = f2bf(dinvt[m] * tanh_fast(c[r]));
        }
    } else {
        float w4v = wf[W4OFF + (wv << 4) + mrow];
        #pragma unroll
        for (int r = 0; r < 4; ++r) {
            float d = tanh_fast(c[r]) * w4v;
            d += __shfl_xor(d, 1); d += __shfl_xor(d, 2);
            d += __shfl_xor(d, 4); d += __shfl_xor(d, 8);
            if (mrow == 0) pd[wv][(quad << 2) + r] = d;
        }
        __syncthreads();
        if (threadIdx.x < 16)
            s4[g * PITCH + tb + threadIdx.x] = dinvt[threadIdx.x] *
                (pd[0][threadIdx.x] + pd[1][threadIdx.x] + pd[2][threadIdx.x] + pd[3][threadIdx.x]);
    }
}

// ---- fused prop(st) + layer0(st+1), PLAIN launch (R8 experiment) ----
// Identical body to R7. Grid 1000 = 4000 waves, 8 blocks/CU capacity (VGPR~48,
// no LDS) => co-resident by construction; monotone-epoch barrier cannot starve.
// Cross-block data inside the kernel is ONLY yin, via relaxed agent-scope 4B
// atomics (LLC coherence point) -> no wbl2/inv anywhere in this kernel.
__global__ __launch_bounds__(256) void k_bridge(
        const float* __restrict__ s4, float* yin, float* __restrict__ yb,
        float* __restrict__ kA, float* __restrict__ kB, float* __restrict__ kC,
        const unsigned short* __restrict__ desc, const int* __restrict__ rowp,
        const float* __restrict__ dinv, const float* __restrict__ wf,
        unsigned short* __restrict__ hout, const int* __restrict__ modes, void* out,
        float c1, float c2, float c3, float c4, int stage, int hidx,
        unsigned be, unsigned* bar) {
    int tid = threadIdx.x, lane = tid & 63, wv = tid >> 6;
    int b = blockIdx.x, g = b & 7, l = b >> 3;
    unsigned nbg = gridDim.x >> 3;
    const float* sg = s4 + g * PITCH;
    float* yg = yin + g * PITCH;
    float b4 = wf[B4OFF];
    int fmode = modes[0];

    // ---- phase A: prop (k, y_next, ŷ) ----
    for (int t = l; t < TILES; t += nbg) {
        #pragma unroll
        for (int r = 0; r < 4; ++r) {
            int local = (t << 4) + (wv << 2) + r;
            int s = rowp[local], e = rowp[local + 1];
            float acc = 0.f;
            for (int i = s + lane; i < e; i += 64) acc += sg[desc[i]];
            #pragma unroll
            for (int off = 32; off; off >>= 1) acc += __shfl_xor(acc, off);
            if (lane == 0) {
                int idx = g * PITCH + local;
                float dv = dinv[local];
                float k = dv * acc + b4;
                float ynew = yb[idx] + c1 * kA[idx] + c2 * kB[idx] + c3 * kC[idx] + c4 * k;
                if (stage == 0) kA[idx] = k;
                else if (stage == 1) kB[idx] = k;
                else if (stage == 2) kC[idx] = k;
                __hip_atomic_store(&yin[idx], dv * ynew, __ATOMIC_RELAXED, __HIP_MEMORY_SCOPE_AGENT);
                if (stage == 3) {
                    yb[idx] = ynew;
                    int cn = g * NNODE + local;
                    if (fmode) ((__hip_bfloat16*)out)[cn * HOR + hidx] = __float2bfloat16(ynew);
                    else       ((float*)out)[cn * HOR + hidx] = ynew;
                }
            }
        }
    }

    // ---- fence-free per-graph barrier (monotone epoch, relaxed atomics only) ----
    __syncthreads();                               // drains each wave's vmcnt -> ŷ at LLC
    if (tid == 0) {
        unsigned* cnt = bar + (g << 8);
        unsigned* ep  = bar + (g << 8) + 64;
        if (__hip_atomic_fetch_add(cnt, 1u, __ATOMIC_RELAXED, __HIP_MEMORY_SCOPE_AGENT) + 1u == be * nbg)
            __hip_atomic_store(ep, be, __ATOMIC_RELAXED, __HIP_MEMORY_SCOPE_AGENT);
        while (__hip_atomic_load(ep, __ATOMIC_RELAXED, __HIP_MEMORY_SCOPE_AGENT) < be)
            __builtin_amdgcn_s_sleep(2);
        asm volatile("" ::: "memory");             // compiler-only ordering fence
    }
    __syncthreads();

    // ---- phase B: layer0 (gather ŷ via LLC-coherent loads, write h0) ----
    float w0 = wf[W0OFF + lane], b0 = wf[B0OFF + lane];
    for (int t = l; t < TILES; t += nbg) {
        #pragma unroll
        for (int r = 0; r < 4; ++r) {
            int local = (t << 4) + (wv << 2) + r;
            int s = rowp[local], e = rowp[local + 1];
            float acc = 0.f;
            for (int i = s + lane; i < e; i += 64)
                acc += __hip_atomic_load(&yg[desc[i]], __ATOMIC_RELAXED, __HIP_MEMORY_SCOPE_AGENT);
            #pragma unroll
            for (int off = 32; off; off >>= 1) acc += __shfl_xor(acc, off);
            float dv = dinv[local];
            float o = dv * tanh_fast(dv * acc * w0 + b0);
            hout[((size_t)(g * PITCH + local) << 6) + lane] = f2bf(o);
        }
    }
}

// ================= host =================

extern "C" void kernel_launch(void* const* d_in, const int* in_sizes, int n_in,
                              void* d_out, int out_size, void* d_ws, size_t ws_size,
                              hipStream_t stream) {
    char* ws = (char*)d_ws;
    unsigned short* desc = (unsigned short*)(ws + OFF_DESC);
    unsigned short* hA   = (unsigned short*)(ws + OFF_HA);
    unsigned short* hB   = (unsigned short*)(ws + OFF_HB);
    float* yin  = (float*)(ws + OFF_YIN);
    float* yb   = (float*)(ws + OFF_YB);
    float* kA   = (float*)(ws + OFF_KA);
    float* kB   = (float*)(ws + OFF_KB);
    float* kC   = (float*)(ws + OFF_KC);
    float* s4   = (float*)(ws + OFF_S4);
    int*   deg  = (int*)(ws + OFF_DEG);
    int*   cur  = (int*)(ws + OFF_CUR);
    int*   rowp = (int*)(ws + OFF_ROWP);
    float* dinv = (float*)(ws + OFF_DINV);
    int*   modes= (int*)(ws + OFF_MODES);
    float* wf   = (float*)(ws + OFF_WF);
    short8* wfrag = (short8*)(ws + OFF_WFRAG);
    unsigned* bar = (unsigned*)(ws + OFF_BAR);

    const void* x    = d_in[0];
    const void* eidx = d_in[1];
    WPtrs wp;
    for (int i = 0; i < 10; ++i) wp.p[i] = d_in[2 + i];

    k_detect  <<<1, 64, 0, stream>>>(x, eidx, modes);
    k_init    <<<PITCH / 256, 256, 0, stream>>>(deg, bar);
    k_count   <<<EPG / 256, 256, 0, stream>>>(eidx, modes, deg);
    k_scan    <<<1, 256, 0, stream>>>(deg, rowp, cur, dinv);
    k_edgefill<<<(ECAP / 2 + 255) / 256, 256, 0, stream>>>((unsigned*)desc);
    k_scatter <<<(EPG + NNODE + 255) / 256, 256, 0, stream>>>(eidx, modes, cur, desc);
    k_convert <<<(WFTOT + 255) / 256, 256, 0, stream>>>(wp, wf, modes);
    k_mkfrag  <<<12, 256, 0, stream>>>(wf, wfrag);
    k_hpad    <<<96, 256, 0, stream>>>((unsigned*)hA, (unsigned*)hB);
    k_finalize<<<NG * PITCH / 256, 256, 0, stream>>>(dinv, x, modes, yin, yb, s4, d_out);

    const float dt = 10.f / 9.f, dt3 = dt / 3.f;
    const float C1[4] = {0.f,  -dt3, dt,  dt * 0.125f};
    const float C2[4] = {0.f,  0.f,  -dt, dt * 0.375f};
    const float C3[4] = {0.f,  0.f,  0.f, dt * 0.375f};
    const float C4[4] = {dt3,  dt,   dt,  dt * 0.125f};

    k_layer0<<<4000, 256, 0, stream>>>(yin, hA, desc, rowp, dinv, wf);  // initial

    unsigned be = 0;
    for (int step = 0; step < NSTEP; ++step) {
        for (int st = 0; st < 4; ++st) {
            k_layer<0><<<1000, 256, 0, stream>>>(hA, hB, nullptr, desc, rowp, dinv, wf, wfrag, 0, B1OFF);
            k_layer<0><<<1000, 256, 0, stream>>>(hB, hA, nullptr, desc, rowp, dinv, wf, wfrag, 1, B2OFF);
            k_layer<1><<<1000, 256, 0, stream>>>(hA, nullptr, s4, desc, rowp, dinv, wf, wfrag, 2, B3OFF);
            ++be;
            k_bridge<<<1000, 256, 0, stream>>>(s4, yin, yb, kA, kB, kC, desc, rowp, dinv, wf,
                                               hA, modes, d_out,
                                               C1[st], C2[st], C3[st], C4[st], st, step + 1,
                                               be, bar);
        }
    }
}

// Round 9
// 1597.022 us; speedup vs baseline: 3.4124x; 1.2094x over previous
//
#include <hip/hip_runtime.h>
#include <hip/hip_bf16.h>

#define NNODE   2000
#define NG      8
#define EPG     64000
#define TSTEPS  24
#define HOR     10
#define NSTEP   (HOR-1)
#define PITCH   2048          // per-graph node pitch; row 2047 is the zero row
#define ECAP    98304         // padded CSR capacity (ushorts)
#define TILES   125           // 2000 / 16

// ---- workspace layout (bytes) ----
#define OFF_DESC    0
#define OFF_HA      196608
#define OFF_HB      2293760
#define OFF_YIN     4390912
#define OFF_YB      4456448
#define OFF_KA      4521984
#define OFF_KB      4587520
#define OFF_KC      4653056
#define OFF_S4      4718592
#define OFF_DEG     4784128
#define OFF_CUR     4792320
#define OFF_ROWP    4800512
#define OFF_DINV    4808960
#define OFF_MODES   4817152
#define OFF_WF      4817408
#define OFF_WFRAG   4868352
// total ~4.92 MB

#define W0OFF 0
#define B0OFF 64
#define W1OFF 128
#define B1OFF 4224
#define W2OFF 4288
#define B2OFF 8384
#define W3OFF 8448
#define B3OFF 12544
#define W4OFF 12608
#define B4OFF 12672
#define WFTOT 12673

typedef __attribute__((ext_vector_type(8))) short short8;
typedef __attribute__((ext_vector_type(4))) float f32x4;

struct WPtrs { const void* p[10]; };

__device__ inline float tanh_fast(float x) {
    float xc = fminf(fmaxf(x, -15.f), 15.f);
    float e  = __expf(2.f * xc);
    return 1.f - 2.f / (e + 1.f);
}
__device__ inline unsigned short f2bf(float f) {
    unsigned u = __float_as_uint(f);
    u += 0x7fff + ((u >> 16) & 1);
    return (unsigned short)(u >> 16);
}
__device__ inline float bf2f(unsigned short h) {
    return __uint_as_float(((unsigned)h) << 16);
}
__device__ inline int ld_idx(const void* p, long i, int imode) {
    return imode ? (int)((const long long*)p)[i] : ((const int*)p)[i];
}

// ================= setup kernels =================

__global__ void k_detect(const void* x, const void* eidx, int* modes) {
    int lane = threadIdx.x;
    const unsigned* xw = (const unsigned*)x;
    unsigned w = xw[lane];
    int ex = (w >> 7) & 0xFF;
    unsigned long long m = __ballot(ex >= 100 && ex <= 145);
    const unsigned* ew = (const unsigned*)eidx;
    unsigned long long m2 = __ballot(ew[2*lane + 1] != 0);
    if (lane == 0) {
        modes[0] = (__popcll(m) >= 48) ? 1 : 0;
        modes[1] = (__popcll(m2) == 0) ? 1 : 0;
    }
}

// merged: deg init + desc sentinel fill + h pad-row zeroing (192 blocks x 256)
__global__ void k_setup0(int* deg, unsigned* desc32, unsigned* hA32, unsigned* hB32) {
    int n = blockIdx.x * 256 + threadIdx.x;
    if (n < PITCH) deg[n] = (n < NNODE) ? 1 : 0;
    if (n < ECAP / 2) desc32[n] = 0x07FF07FFu;     // sentinel -> zero row 2047
    if (n < 2 * NG * 48 * 32) {
        int b = n / (NG * 48 * 32), r = n % (NG * 48 * 32);
        int g = r / (48 * 32), rr = r % (48 * 32);
        int row = NNODE + rr / 32, fp = rr % 32;
        unsigned* pp = b ? hB32 : hA32;
        pp[(g * PITCH + row) * 32 + fp] = 0;
    }
}

__global__ void k_count(const void* eidx, const int* __restrict__ modes, int* deg) {
    int e = blockIdx.x * 256 + threadIdx.x;
    int imode = modes[1];
    int dst = ld_idx(eidx, (long)EPG + e, imode);
    atomicAdd(&deg[dst], 1);
}

__global__ __launch_bounds__(256) void k_scan(const int* __restrict__ deg, int* rowp,
                                              int* cursor, float* dinv) {
    __shared__ int part[256];
    int t = threadIdx.x, base = t * 8;
    int loc[8]; int s = 0;
    #pragma unroll
    for (int k = 0; k < 8; ++k) {
        int d = deg[base + k];
        int p = (d + 15) & ~15;
        loc[k] = p; s += p;
    }
    part[t] = s; __syncthreads();
    for (int off = 1; off < 256; off <<= 1) {
        int v = (t >= off) ? part[t - off] : 0;
        __syncthreads();
        part[t] += v;
        __syncthreads();
    }
    int run = part[t] - s;
    #pragma unroll
    for (int k = 0; k < 8; ++k) {
        rowp[base + k] = run; cursor[base + k] = run;
        int d = deg[base + k];
        dinv[base + k] = (d > 0) ? rsqrtf((float)d) : 0.f;
        run += loc[k];
    }
    if (t == 255) rowp[PITCH] = part[255];
}

__global__ void k_scatter(const void* eidx, const int* __restrict__ modes,
                          int* cursor, unsigned short* desc) {
    int idx = blockIdx.x * 256 + threadIdx.x;
    if (idx >= EPG + NNODE) return;
    int imode = modes[1];
    int s, d;
    if (idx < EPG) { s = ld_idx(eidx, idx, imode); d = ld_idx(eidx, (long)EPG + idx, imode); }
    else           { s = idx - EPG; d = s; }
    int pos = atomicAdd(&cursor[d], 1);
    desc[pos] = (unsigned short)s;
}

__global__ void k_convert(WPtrs wp, float* wf, const int* __restrict__ modes) {
    int idx = blockIdx.x * 256 + threadIdx.x;
    if (idx >= WFTOT) return;
    int fmode = modes[0];
    const int offs[10]  = {W0OFF,B0OFF,W1OFF,B1OFF,W2OFF,B2OFF,W3OFF,B3OFF,W4OFF,B4OFF};
    const int sizes[10] = {64,64,4096,64,4096,64,4096,64,64,1};
    #pragma unroll
    for (int s = 0; s < 10; ++s) {
        if (idx >= offs[s] && idx < offs[s] + sizes[s]) {
            int j = idx - offs[s];
            wf[idx] = fmode ? __bfloat162float(((const __hip_bfloat16*)wp.p[s])[j])
                            : ((const float*)wp.p[s])[j];
        }
    }
}

__global__ void k_mkfrag(const float* __restrict__ wf, short8* frag) {
    int t = blockIdx.x * 256 + threadIdx.x;
    if (t >= 3072) return;
    int lane = t & 63, half = (t >> 6) & 1, kh = (t >> 7) & 1, nb = (t >> 8) & 3, mat = t >> 10;
    const int woffs[3] = {W1OFF, W2OFF, W3OFF};
    const float* W = wf + woffs[mat];
    int n  = nb * 16 + (lane & 15);
    int k0 = kh * 32 + (lane >> 4) * 8;
    short8 v;
    #pragma unroll
    for (int j = 0; j < 8; ++j) {
        float w = W[(k0 + j) * 64 + n];
        unsigned short h = f2bf(w);
        v[j] = half ? (short)f2bf(w - bf2f(h)) : (short)h;
    }
    frag[t] = v;
}

__global__ void k_finalize(const float* __restrict__ dinv, const void* x,
                           const int* __restrict__ modes,
                           float* yin, float* yb, float* s4, void* out) {
    int idx = blockIdx.x * 256 + threadIdx.x;
    if (idx >= NG * PITCH) return;
    int g = idx >> 11, local = idx & (PITCH - 1);
    if (local >= NNODE) { yin[idx] = 0.f; yb[idx] = 0.f; s4[idx] = 0.f; return; }
    int cn = g * NNODE + local;
    float y0 = modes[0] ? __bfloat162float(((const __hip_bfloat16*)x)[cn * TSTEPS + (TSTEPS - 1)])
                        : ((const float*)x)[cn * TSTEPS + (TSTEPS - 1)];
    yin[idx] = dinv[local] * y0;
    yb[idx]  = y0;
    if (modes[0]) ((__hip_bfloat16*)out)[cn * HOR] = __float2bfloat16(y0);
    else          ((float*)out)[cn * HOR] = y0;
}

// ---- layer 0: scalar gather of yin' -> h0' (bf16) ----
__global__ __launch_bounds__(256) void k_layer0(
        const float* __restrict__ yin, unsigned short* __restrict__ hout,
        const unsigned short* __restrict__ desc, const int* __restrict__ rowp,
        const float* __restrict__ dinv, const float* __restrict__ wf) {
    int lane = threadIdx.x & 63, wv = threadIdx.x >> 6;
    int b = blockIdx.x;
    int g = b & 7, local = (b >> 3) * 4 + wv;
    const float* yg = yin + g * PITCH;
    int s = rowp[local], e = rowp[local + 1];
    float acc = 0.f;
    for (int i = s + lane; i < e; i += 64) acc += yg[desc[i]];
    #pragma unroll
    for (int off = 32; off; off >>= 1) acc += __shfl_xor(acc, off);
    float dv = dinv[local];
    float o = dv * tanh_fast(dv * acc * wf[W0OFF + lane] + wf[B0OFF + lane]);
    hout[((g * PITCH + local) << 6) + lane] = f2bf(o);
}

// ---- heavy layers (R9): dword 2-feat gather; fp=lane&31 feature-pair, p=lane>>5
//      edge parity. One dword load covers 2 edges; accL/accH are two independent
//      chains; combine with shfl_xor(32). MFMA transform unchanged (R4-proven). ----
template<int FUSE>
__global__ __launch_bounds__(256, 4) void k_layer(
        const unsigned short* __restrict__ hin, unsigned short* __restrict__ hout,
        float* __restrict__ s4,
        const unsigned short* __restrict__ desc, const int* __restrict__ rowp,
        const float* __restrict__ dinv, const float* __restrict__ wf,
        const short8* __restrict__ frag, int mat, int boff) {
    __shared__ float tile[16 * 68];
    __shared__ float dinvt[16];
    __shared__ float pd[4][16];
    int lane = threadIdx.x & 63, wv = threadIdx.x >> 6;
    int b = blockIdx.x;
    int g = b & 7, tb = (b >> 3) << 4;
    const unsigned* hg32 = (const unsigned*)(hin + ((size_t)g * PITCH << 6));

    const short8* fb = frag + (mat << 10);
    short8 Bh0 = fb[(wv << 8) +   0 + lane];
    short8 Bl0 = fb[(wv << 8) +  64 + lane];
    short8 Bh1 = fb[(wv << 8) + 128 + lane];
    short8 Bl1 = fb[(wv << 8) + 192 + lane];

    int fp = lane & 31, p = lane >> 5;
    unsigned psh = (unsigned)(p << 4);             // 0 or 16: edge-parity extract shift

    #pragma unroll
    for (int r = 0; r < 4; ++r) {
        int m = (wv << 2) + r;
        int local = tb + m;
        int s = rowp[local], e = rowp[local + 1];  // multiples of 16
        float accL = 0.f, accH = 0.f;              // feats 2fp, 2fp+1
        for (int i = s; i < e; i += 16) {
            uint4 q0 = *(const uint4*)(desc + i);      // edges i..i+7   (2/uint)
            uint4 q1 = *(const uint4*)(desc + i + 8);  // edges i+8..i+15
            unsigned sidx[8];
            sidx[0] = (q0.x >> psh) & 0xffffu;
            sidx[1] = (q0.y >> psh) & 0xffffu;
            sidx[2] = (q0.z >> psh) & 0xffffu;
            sidx[3] = (q0.w >> psh) & 0xffffu;
            sidx[4] = (q1.x >> psh) & 0xffffu;
            sidx[5] = (q1.y >> psh) & 0xffffu;
            sidx[6] = (q1.z >> psh) & 0xffffu;
            sidx[7] = (q1.w >> psh) & 0xffffu;
            unsigned v[8];
            #pragma unroll
            for (int j = 0; j < 8; ++j) v[j] = hg32[(sidx[j] << 5) + fp];
            #pragma unroll
            for (int j = 0; j < 8; ++j) {
                accL += __uint_as_float(v[j] << 16);        // bf16 low -> f32
                accH += __uint_as_float(v[j] & 0xffff0000u);// bf16 high -> f32
            }
        }
        float dv = dinv[local];
        accL *= dv; accH *= dv;
        accL += __shfl_xor(accL, 32);
        accH += __shfl_xor(accH, 32);
        if (p == 0) {
            float2* dst = (float2*)&tile[m * 68 + (fp << 1)];
            *dst = make_float2(accL, accH);
        }
        if (lane == 0) dinvt[m] = dv;
    }
    __syncthreads();

    int mrow = lane & 15, quad = lane >> 4;
    const float* arow = &tile[mrow * 68];
    float4 a0 = *(const float4*)(arow + (quad << 3));
    float4 a1 = *(const float4*)(arow + (quad << 3) + 4);
    float4 a2 = *(const float4*)(arow + 32 + (quad << 3));
    float4 a3 = *(const float4*)(arow + 32 + (quad << 3) + 4);
    float av0[8] = {a0.x, a0.y, a0.z, a0.w, a1.x, a1.y, a1.z, a1.w};
    float av1[8] = {a2.x, a2.y, a2.z, a2.w, a3.x, a3.y, a3.z, a3.w};
    short8 Ah0, Al0, Ah1, Al1;
    #pragma unroll
    for (int j = 0; j < 8; ++j) {
        unsigned short h0 = f2bf(av0[j]);
        Ah0[j] = (short)h0; Al0[j] = (short)f2bf(av0[j] - bf2f(h0));
        unsigned short h1 = f2bf(av1[j]);
        Ah1[j] = (short)h1; Al1[j] = (short)f2bf(av1[j] - bf2f(h1));
    }
    float bias = wf[boff + (wv << 4) + mrow];
    f32x4 c = {bias, bias, bias, bias};
    c = __builtin_amdgcn_mfma_f32_16x16x32_bf16(Ah0, Bh0, c, 0, 0, 0);
    c = __builtin_amdgcn_mfma_f32_16x16x32_bf16(Al0, Bh0, c, 0, 0, 0);
    c = __builtin_amdgcn_mfma_f32_16x16x32_bf16(Ah0, Bl0, c, 0, 0, 0);
    c = __builtin_amdgcn_mfma_f32_16x16x32_bf16(Ah1, Bh1, c, 0, 0, 0);
    c = __builtin_amdgcn_mfma_f32_16x16x32_bf16(Al1, Bh1, c, 0, 0, 0);
    c = __builtin_amdgcn_mfma_f32_16x16x32_bf16(Ah1, Bl1, c, 0, 0, 0);

    if (!FUSE) {
        #pragma unroll
        for (int r = 0; r < 4; ++r) {
            int m = (quad << 2) + r;
            hout[(((size_t)g * PITCH + tb + m) << 6) + (wv << 4) + mrow] = f2bf(dinvt[m] * tanh_fast(c[r]));
        }
    } else {
        float w4v = wf[W4OFF + (wv << 4) + mrow];
        #pragma unroll
        for (int r = 0; r < 4; ++r) {
            float d = tanh_fast(c[r]) * w4v;
            d += __shfl_xor(d, 1); d += __shfl_xor(d, 2);
            d += __shfl_xor(d, 4); d += __shfl_xor(d, 8);
            if (mrow == 0) pd[wv][(quad << 2) + r] = d;
        }
        __syncthreads();
        if (threadIdx.x < 16)
            s4[g * PITCH + tb + threadIdx.x] = dinvt[threadIdx.x] *
                (pd[0][threadIdx.x] + pd[1][threadIdx.x] + pd[2][threadIdx.x] + pd[3][threadIdx.x]);
    }
}

// ---- final propagation + RK4 stage combine (R4-proven plain kernel) ----
__global__ __launch_bounds__(256) void k_prop(
        const float* __restrict__ s4, const unsigned short* __restrict__ desc,
        const int* __restrict__ rowp, const float* __restrict__ dinv,
        const float* __restrict__ wf,
        float* yin, float* yb, float* kA, float* kB, float* kC,
        float c1, float c2, float c3, float c4, int stage,
        const int* __restrict__ modes, void* out, int hidx) {
    int lane = threadIdx.x & 63, wv = threadIdx.x >> 6;
    int b = blockIdx.x;
    int g = b & 7, local = (b >> 3) * 4 + wv;
    const float* sg = s4 + g * PITCH;
    int s = rowp[local], e = rowp[local + 1];
    float acc = 0.f;
    for (int i = s + lane; i < e; i += 64) acc += sg[desc[i]];
    #pragma unroll
    for (int off = 32; off; off >>= 1) acc += __shfl_xor(acc, off);
    if (lane == 0) {
        int idx = g * PITCH + local;
        float dv = dinv[local];
        float k = dv * acc + wf[B4OFF];
        float ynew = yb[idx] + c1 * kA[idx] + c2 * kB[idx] + c3 * kC[idx] + c4 * k;
        if (stage == 0) kA[idx] = k;
        else if (stage == 1) kB[idx] = k;
        else if (stage == 2) kC[idx] = k;
        yin[idx] = dv * ynew;
        if (stage == 3) {
            yb[idx] = ynew;
            int cn = g * NNODE + local;
            if (modes[0]) ((__hip_bfloat16*)out)[cn * HOR + hidx] = __float2bfloat16(ynew);
            else          ((float*)out)[cn * HOR + hidx] = ynew;
        }
    }
}

// ================= host =================

extern "C" void kernel_launch(void* const* d_in, const int* in_sizes, int n_in,
                              void* d_out, int out_size, void* d_ws, size_t ws_size,
                              hipStream_t stream) {
    char* ws = (char*)d_ws;
    unsigned short* desc = (unsigned short*)(ws + OFF_DESC);
    unsigned short* hA   = (unsigned short*)(ws + OFF_HA);
    unsigned short* hB   = (unsigned short*)(ws + OFF_HB);
    float* yin  = (float*)(ws + OFF_YIN);
    float* yb   = (float*)(ws + OFF_YB);
    float* kA   = (float*)(ws + OFF_KA);
    float* kB   = (float*)(ws + OFF_KB);
    float* kC   = (float*)(ws + OFF_KC);
    float* s4   = (float*)(ws + OFF_S4);
    int*   deg  = (int*)(ws + OFF_DEG);
    int*   cur  = (int*)(ws + OFF_CUR);
    int*   rowp = (int*)(ws + OFF_ROWP);
    float* dinv = (float*)(ws + OFF_DINV);
    int*   modes= (int*)(ws + OFF_MODES);
    float* wf   = (float*)(ws + OFF_WF);
    short8* wfrag = (short8*)(ws + OFF_WFRAG);

    const void* x    = d_in[0];
    const void* eidx = d_in[1];
    WPtrs wp;
    for (int i = 0; i < 10; ++i) wp.p[i] = d_in[2 + i];

    k_detect  <<<1, 64, 0, stream>>>(x, eidx, modes);
    k_setup0  <<<192, 256, 0, stream>>>(deg, (unsigned*)desc, (unsigned*)hA, (unsigned*)hB);
    k_count   <<<EPG / 256, 256, 0, stream>>>(eidx, modes, deg);
    k_scan    <<<1, 256, 0, stream>>>(deg, rowp, cur, dinv);
    k_scatter <<<(EPG + NNODE + 255) / 256, 256, 0, stream>>>(eidx, modes, cur, desc);
    k_convert <<<(WFTOT + 255) / 256, 256, 0, stream>>>(wp, wf, modes);
    k_mkfrag  <<<12, 256, 0, stream>>>(wf, wfrag);
    k_finalize<<<NG * PITCH / 256, 256, 0, stream>>>(dinv, x, modes, yin, yb, s4, d_out);

    const float dt = 10.f / 9.f, dt3 = dt / 3.f;
    const float C1[4] = {0.f,  -dt3, dt,  dt * 0.125f};
    const float C2[4] = {0.f,  0.f,  -dt, dt * 0.375f};
    const float C3[4] = {0.f,  0.f,  0.f, dt * 0.375f};
    const float C4[4] = {dt3,  dt,   dt,  dt * 0.125f};

    k_layer0<<<4000, 256, 0, stream>>>(yin, hA, desc, rowp, dinv, wf);  // initial

    for (int step = 0; step < NSTEP; ++step) {
        for (int st = 0; st < 4; ++st) {
            k_layer<0><<<1000, 256, 0, stream>>>(hA, hB, nullptr, desc, rowp, dinv, wf, wfrag, 0, B1OFF);
            k_layer<0><<<1000, 256, 0, stream>>>(hB, hA, nullptr, desc, rowp, dinv, wf, wfrag, 1, B2OFF);
            k_layer<1><<<1000, 256, 0, stream>>>(hA, nullptr, s4, desc, rowp, dinv, wf, wfrag, 2, B3OFF);
            k_prop    <<<4000, 256, 0, stream>>>(s4, desc, rowp, dinv, wf, yin, yb, kA, kB, kC,
                                                 C1[st], C2[st], C3[st], C4[st], st,
                                                 modes, d_out, step + 1);
            if (step < NSTEP - 1 || st < 3)
                k_layer0<<<4000, 256, 0, stream>>>(yin, hA, desc, rowp, dinv, wf);
        }
    }
}